// Round 6
// baseline (147.883 us; speedup 1.0000x reference)
//
#include <hip/hip_runtime.h>

#define NQ 12
#define NL 4
#define NGATES (NQ * NL)

// ---------------------------------------------------------------------------
// Physical slot y (12 bits): bit 11 = wave, bits 10..5 = lane, bits 4..0 = reg.
// GF(2) re-label vs the natural layout p: y_j = p_j (j<=10),
// y_11 = p_8^p_9^p_10^p_11  (invertible). Chosen so only FIVE of the 36
// active gate masks touch the wave bit (LDS exchange); was eight.
// Gate masks transform covariantly:  m' = (m&0x7FF) | (par(m&0xF00)<<11).
// Z parity rows contravariantly:     r' = (r&0x7FF) ^ (r&0x800 ? 0xF00 : 0).
// Init: logical l = P^-1 y =>  l_j = y_j (j<=10), l_11 = y_8^y_9^y_10^y_11,
// so qubit 0's bit = wv ^ parity(lane & 0x38); all other qubits unchanged.
// Layer-1 RX folded into the initial product state (gates 0..11 skipped).
// Cross-lane: DPP / permlane16/32_swap (VALU pipe). sched_barrier(0) between
// gates prevents the scheduler from hoisting all sincos/temps (the round-2/5
// spill source: demand ~164 regs vs 128 budget -> 75 MB scratch traffic).
// ---------------------------------------------------------------------------
struct Masks { unsigned rx[NGATES]; unsigned z[NQ]; };

constexpr Masks compute_masks() {
  Masks mk{};
  unsigned col[NQ] = {};
  for (int b = 0; b < NQ; ++b) col[b] = 1u << b;
  int g = 0;
  for (int l = 0; l < NL; ++l) {
    for (int w = 0; w < NQ; ++w) mk.rx[g++] = col[NQ - 1 - w];
    for (int i = 0; i < NQ; ++i) {           // ring CNOT(i, (i+1)%12)
      int cb = NQ - 1 - i;
      int tb = NQ - 1 - ((i + 1) % NQ);
      col[cb] ^= col[tb];
    }
  }
  unsigned A[NQ] = {}, Inv[NQ] = {};
  for (int i = 0; i < NQ; ++i) {
    unsigned rowv = 0;
    for (int j = 0; j < NQ; ++j) rowv |= ((col[j] >> i) & 1u) << j;
    A[i] = rowv;
    Inv[i] = 1u << i;
  }
  for (int c = 0; c < NQ; ++c) {
    int piv = c;
    while (((A[piv] >> c) & 1u) == 0u) ++piv;
    unsigned ta = A[piv]; A[piv] = A[c]; A[c] = ta;
    unsigned ti = Inv[piv]; Inv[piv] = Inv[c]; Inv[c] = ti;
    for (int r = 0; r < NQ; ++r)
      if (r != c && ((A[r] >> c) & 1u)) { A[r] ^= A[c]; Inv[r] ^= Inv[c]; }
  }
  for (int w = 0; w < NQ; ++w) mk.z[w] = Inv[NQ - 1 - w];
  // GF(2) re-label: wave coordinate = parity of bits 8..11.
  for (int i = 0; i < NGATES; ++i) {
    unsigned m = mk.rx[i];
    unsigned par = (unsigned)(__builtin_popcount(m & 0xF00u) & 1);
    mk.rx[i] = (m & 0x7FFu) | (par << 11);
  }
  for (int w = 0; w < NQ; ++w) {
    unsigned r = mk.z[w];
    mk.z[w] = (r & 0x7FFu) ^ ((r & 0x800u) ? 0xF00u : 0u);
  }
  return mk;
}

constexpr Masks MK = compute_masks();

typedef float v2f __attribute__((ext_vector_type(2)));
typedef int   v2i __attribute__((ext_vector_type(2)));

template <int CTRL>
__device__ __forceinline__ int dpp_i(int x) {
  return __builtin_amdgcn_update_dpp(x, x, CTRL, 0xf, 0xf, false);
}

// v[lane ^ ML] on the VALU pipe. quad_perm xor1=0xB1 xor2=0x4E xor3=0x1B;
// row_half_mirror(xor7)=0x141; row_ror:8(xor8)=0x128; row_mirror(xor15)=0x140.
template <int ML>
__device__ __forceinline__ float fetchx(float v) {
  static_assert(ML >= 1 && ML < 64, "lane mask");
  int x = __float_as_int(v);
  constexpr int m4 = ML & 15;
  if constexpr (m4 == 1)       x = dpp_i<0xB1>(x);
  else if constexpr (m4 == 2)  x = dpp_i<0x4E>(x);
  else if constexpr (m4 == 3)  x = dpp_i<0x1B>(x);
  else if constexpr (m4 == 4)  { x = dpp_i<0x141>(x); x = dpp_i<0x1B>(x); }
  else if constexpr (m4 == 5)  { x = dpp_i<0x141>(x); x = dpp_i<0x4E>(x); }
  else if constexpr (m4 == 6)  { x = dpp_i<0x141>(x); x = dpp_i<0xB1>(x); }
  else if constexpr (m4 == 7)  x = dpp_i<0x141>(x);
  else if constexpr (m4 == 8)  x = dpp_i<0x128>(x);
  else if constexpr (m4 == 9)  { x = dpp_i<0x128>(x); x = dpp_i<0xB1>(x); }
  else if constexpr (m4 == 10) { x = dpp_i<0x128>(x); x = dpp_i<0x4E>(x); }
  else if constexpr (m4 == 11) { x = dpp_i<0x128>(x); x = dpp_i<0x1B>(x); }
  else if constexpr (m4 == 12) { x = dpp_i<0x140>(x); x = dpp_i<0x1B>(x); }
  else if constexpr (m4 == 13) { x = dpp_i<0x140>(x); x = dpp_i<0x4E>(x); }
  else if constexpr (m4 == 14) { x = dpp_i<0x140>(x); x = dpp_i<0xB1>(x); }
  else if constexpr (m4 == 15) x = dpp_i<0x140>(x);
  if constexpr (ML & 16) {
    v2i r = __builtin_amdgcn_permlane16_swap(x, x, false, false);
    x = (threadIdx.x & 16) ? r.x : r.y;
  }
  if constexpr (ML & 32) {
    v2i r = __builtin_amdgcn_permlane32_swap(x, x, false, false);
    x = (threadIdx.x & 32) ? r.x : r.y;
  }
  return __int_as_float(x);
}

// cur' = c*cur + (s,-s)*(t=(partner.im, partner.re))
__device__ __forceinline__ v2f rxup(v2f cur, float c, v2f sv, float tx, float ty) {
  v2f o;
  o.x = fmaf(sv.x, tx, c * cur.x);
  o.y = fmaf(sv.y, ty, c * cur.y);
  return o;
}

// Cross-wave exchange, one 8-amp chunk as 4 float4. Alternating buffers give
// one barrier per chunk (buffer of chunk c reused at c+2; its writers have
// passed barrier c+1, which readers of chunk c reached only after reading).
template <int CH, int ML>
__device__ __forceinline__ void xchg_chunk(v2f (&st)[32], float c, v2f sv,
                                           float4* xbuf, int tid) {
  float4* buf = xbuf + (CH & 1) * (4 * 128);
  constexpr int base = CH * 8;
#pragma unroll
  for (int j = 0; j < 4; ++j)
    buf[j * 128 + tid] = make_float4(st[base + 2 * j].x, st[base + 2 * j].y,
                                     st[base + 2 * j + 1].x, st[base + 2 * j + 1].y);
  __syncthreads();
  const int ptid = tid ^ (64 | ML);
  float4 g[4];
#pragma unroll
  for (int j = 0; j < 4; ++j) g[j] = buf[j * 128 + ptid];
#pragma unroll
  for (int j = 0; j < 4; ++j) {
    st[base + 2 * j]     = rxup(st[base + 2 * j],     c, sv, g[j].y, g[j].x);
    st[base + 2 * j + 1] = rxup(st[base + 2 * j + 1], c, sv, g[j].w, g[j].z);
  }
}

template <int G>
__device__ __forceinline__ void apply_gate(v2f (&st)[32], float c, v2f sv,
                                           float4* xbuf, int tid) {
  constexpr unsigned m = MK.rx[G];
  constexpr int mw = (int)((m >> 11) & 1u);
  constexpr int ml = (int)((m >> 5) & 63u);
  constexpr int mr = (int)(m & 31u);
  if constexpr (mw) {
    static_assert(mr == 0, "crossing gates have pure-lane low masks");
    xchg_chunk<0, ml>(st, c, sv, xbuf, tid);
    xchg_chunk<1, ml>(st, c, sv, xbuf, tid);
    xchg_chunk<2, ml>(st, c, sv, xbuf, tid);
    xchg_chunk<3, ml>(st, c, sv, xbuf, tid);
  } else if constexpr (ml == 0) {
    // in-register pairing
#pragma unroll
    for (int r = 0; r < 32; ++r) {
      const int r2 = r ^ mr;
      if (r < r2) {
        v2f a = st[r], b = st[r2];
        st[r]  = rxup(a, c, sv, b.y, b.x);
        st[r2] = rxup(b, c, sv, a.y, a.x);
      }
    }
  } else if constexpr (mr == 0) {
    // pure cross-lane
#pragma unroll
    for (int r = 0; r < 32; ++r) {
      float ty = fetchx<ml>(st[r].x);
      float tx = fetchx<ml>(st[r].y);
      st[r] = rxup(st[r], c, sv, tx, ty);
    }
  } else {
    // mixed: partner is register r^mr on lane^ml
#pragma unroll
    for (int r = 0; r < 32; ++r) {
      const int r2 = r ^ mr;
      if (r < r2) {
        float t1x = fetchx<ml>(st[r2].y);
        float t1y = fetchx<ml>(st[r2].x);
        float t2x = fetchx<ml>(st[r].y);
        float t2y = fetchx<ml>(st[r].x);
        st[r]  = rxup(st[r],  c, sv, t1x, t1y);
        st[r2] = rxup(st[r2], c, sv, t2x, t2y);
      }
    }
  }
}

template <int G>
__device__ __forceinline__ void run_gates(v2f (&st)[32],
                                          const float* __restrict__ wts,
                                          float4* xbuf, int tid) {
  if constexpr (G < NGATES) {
    __builtin_amdgcn_sched_barrier(0);   // keep each gate's temps inside it
    float s, c;
    __sincosf(wts[G] * 0.5f, &s, &c);
    v2f sv; sv.x = s; sv.y = -s;
    apply_gate<G>(st, c, sv, xbuf, tid);
    run_gates<G + 1>(st, wts, xbuf, tid);
  }
}

template <int W>
__device__ __forceinline__ void expvals(const float (&a2)[32], int lane, int wv,
                                        float* zb) {
  if constexpr (W < NQ) {
    constexpr unsigned zm = MK.z[W];
    constexpr int zr = (int)(zm & 31u);
    constexpr int zl = (int)((zm >> 5) & 63u);
    constexpr int zw = (int)((zm >> 11) & 1u);
    float acc = 0.f;
#pragma unroll
    for (int r = 0; r < 32; ++r) {
      if (__builtin_popcount((unsigned)(r & zr)) & 1) acc -= a2[r];
      else                                            acc += a2[r];
    }
    if (__popc(lane & zl) & 1) acc = -acc;
    if constexpr (zw) { if (wv) acc = -acc; }
    acc += fetchx<32>(acc);
    acc += fetchx<16>(acc);
    acc += fetchx<8>(acc);
    acc += fetchx<4>(acc);
    acc += fetchx<2>(acc);
    acc += fetchx<1>(acc);
    if (lane == 0) zb[wv * NQ + W] = acc;
    expvals<W + 1>(a2, lane, wv, zb);
  }
}

__global__ __attribute__((amdgpu_flat_work_group_size(128, 128),
                          amdgpu_waves_per_eu(4, 4)))
void qsim_kernel(const float* __restrict__ x, const float* __restrict__ wts,
                 float* __restrict__ out) {
  __shared__ float4 xbuf[2 * 4 * 128];   // 16 KiB exchange double-buffer
  __shared__ float zb[2 * NQ];

  const int bidx = blockIdx.x;           // one batch element per 128-thr block
  const int tid  = threadIdx.x;
  const int lane = tid & 63;
  const int wv   = tid >> 6;

  const float4* xv = reinterpret_cast<const float4*>(x + bidx * NQ);
  float4 q0 = xv[0], q1 = xv[1], q2 = xv[2];
  const float xa[NQ] = {q0.x, q0.y, q0.z, q0.w, q1.x, q1.y, q1.z, q1.w,
                        q2.x, q2.y, q2.z, q2.w};

  // Per-qubit factor after RY(x_w) then layer-1 RX(wts[w]):
  //   bit=0: (c*cy, -s*sy)   bit=1: (c*sy, -s*cy)
  // Qubit 0's bit under the re-label: wv ^ parity(lane & 0x38).
  float lr, li;
  {
    float sy, cy, s, c;
    __sincosf(xa[0] * 0.5f, &sy, &cy);
    __sincosf(wts[0] * 0.5f, &s, &c);
    const int b0 = (wv ^ __popc(lane & 0x38)) & 1;
    lr = b0 ? c * sy : c * cy;
    li = b0 ? -s * cy : -s * sy;
#pragma unroll
    for (int w = 1; w <= 6; ++w) {
      __sincosf(xa[w] * 0.5f, &sy, &cy);
      __sincosf(wts[w] * 0.5f, &s, &c);
      const int b = (lane >> (6 - w)) & 1;
      float gr = b ? c * sy : c * cy;
      float gi = b ? -s * cy : -s * sy;
      float nr = lr * gr - li * gi;
      float ni = lr * gi + li * gr;
      lr = nr; li = ni;
    }
  }

  // reg bit j = qubit 11-j, j=0..4: complex recursive doubling
  float g0r[5], g0i[5], g1r[5], g1i[5];
#pragma unroll
  for (int j = 0; j < 5; ++j) {
    const int w = 11 - j;
    float sy, cy, s, c;
    __sincosf(xa[w] * 0.5f, &sy, &cy);
    __sincosf(wts[w] * 0.5f, &s, &c);
    g0r[j] = c * cy;  g0i[j] = -s * sy;
    g1r[j] = c * sy;  g1i[j] = -s * cy;
  }

  v2f st[32];
  st[0].x = lr; st[0].y = li;
#pragma unroll
  for (int j = 0; j < 5; ++j) {
#pragma unroll
    for (int k = 0; k < 32; ++k) {
      if (k < (1 << j)) {
        float ar = st[k].x, ai = st[k].y;
        st[k | (1 << j)].x = ar * g1r[j] - ai * g1i[j];
        st[k | (1 << j)].y = ar * g1i[j] + ai * g1r[j];
        st[k].x = ar * g0r[j] - ai * g0i[j];
        st[k].y = ar * g0i[j] + ai * g0r[j];
      }
    }
  }

  run_gates<NQ>(st, wts, xbuf, tid);   // layers 2..4 (gates 12..47)
  __builtin_amdgcn_sched_barrier(0);

  float a2[32];
#pragma unroll
  for (int r = 0; r < 32; ++r) a2[r] = fmaf(st[r].x, st[r].x, st[r].y * st[r].y);

  expvals<0>(a2, lane, wv, zb);
  __syncthreads();
  if (tid < NQ) out[bidx * NQ + tid] = zb[tid] + zb[NQ + tid];
}

extern "C" void kernel_launch(void* const* d_in, const int* in_sizes, int n_in,
                              void* d_out, int out_size, void* d_ws, size_t ws_size,
                              hipStream_t stream) {
  const float* x   = (const float*)d_in[0];   // (4096, 12) f32
  const float* wts = (const float*)d_in[1];   // (4, 12) f32
  float* out = (float*)d_out;                 // (4096, 12) f32

  const int batch = in_sizes[0] / NQ;         // 4096
  dim3 grid(batch);
  dim3 block(128);
  qsim_kernel<<<grid, block, 0, stream>>>(x, wts, out);
}

// Round 7
// 143.955 us; speedup vs baseline: 1.0273x; 1.0273x over previous
//
#include <hip/hip_runtime.h>

#define NQ 12
#define NL 4
#define NGATES (NQ * NL)

// ---------------------------------------------------------------------------
// 256 threads per batch element; 16 amps/thread (32 VGPR state -> fits the
// 64-reg arch half, no AGPR traffic, no scratch; 8 waves/EU).
// Physical p (12 bits, logical basis index at t=0). Hardware slot coords:
//   w1 = parity(p & 0xFFE)   (tid bit 7)
//   w0 = p0                  (tid bit 6)
//   lane bits l5..l0 = p10..p5  (tid bits 5..0)
//   reg  bits r3..r0 = p4..p1   (amp index 0..15)
// This wave-covector pair {e0, 0xFFE} minimizes wave-crossing gates: 9 of 36
// (natural labeling: 12). Gate masks m transform covariantly:
//   m' = (parity(m&0xFFE)<<11) | (m & 0x7FF)     (bit0 = w0-xor)
// Z parity rows contravariantly: z' = z&0x800 ? z^0x7FE : z.
// Init product state: qubit 0's bit = w1 ^ par(lane) ^ par(r); qubit 11 = w0;
// qubits 1..6 = lane bits 5..0; qubits 7..10 = reg bits r3..r0.
// Layer-1 RX folded into the initial product state (gates 0..11 skipped).
// Cross-lane: DPP / permlane16/32_swap (VALU pipe only). LDS exchange:
// float4-packed chunks, alternating 8KB buffers, one barrier per chunk.
// ---------------------------------------------------------------------------
struct Masks { unsigned rx[NGATES]; unsigned z[NQ]; };

constexpr Masks compute_masks() {
  Masks mk{};
  unsigned col[NQ] = {};
  for (int b = 0; b < NQ; ++b) col[b] = 1u << b;
  int g = 0;
  for (int l = 0; l < NL; ++l) {
    for (int w = 0; w < NQ; ++w) mk.rx[g++] = col[NQ - 1 - w];
    for (int i = 0; i < NQ; ++i) {           // ring CNOT(i, (i+1)%12)
      int cb = NQ - 1 - i;
      int tb = NQ - 1 - ((i + 1) % NQ);
      col[cb] ^= col[tb];
    }
  }
  unsigned A[NQ] = {}, Inv[NQ] = {};
  for (int i = 0; i < NQ; ++i) {
    unsigned rowv = 0;
    for (int j = 0; j < NQ; ++j) rowv |= ((col[j] >> i) & 1u) << j;
    A[i] = rowv;
    Inv[i] = 1u << i;
  }
  for (int c = 0; c < NQ; ++c) {
    int piv = c;
    while (((A[piv] >> c) & 1u) == 0u) ++piv;
    unsigned ta = A[piv]; A[piv] = A[c]; A[c] = ta;
    unsigned ti = Inv[piv]; Inv[piv] = Inv[c]; Inv[c] = ti;
    for (int r = 0; r < NQ; ++r)
      if (r != c && ((A[r] >> c) & 1u)) { A[r] ^= A[c]; Inv[r] ^= Inv[c]; }
  }
  for (int w = 0; w < NQ; ++w) mk.z[w] = Inv[NQ - 1 - w];
  // relabel
  for (int i = 0; i < NGATES; ++i) {
    unsigned m = mk.rx[i];
    unsigned w1 = (unsigned)(__builtin_popcount(m & 0xFFEu) & 1);
    mk.rx[i] = (w1 << 11) | (m & 0x7FFu);
  }
  for (int w = 0; w < NQ; ++w) {
    unsigned z = mk.z[w];
    mk.z[w] = (z & 0x800u) ? (z ^ 0x7FEu) : z;
  }
  return mk;
}

constexpr Masks MK = compute_masks();

typedef float v2f __attribute__((ext_vector_type(2)));
typedef int   v2i __attribute__((ext_vector_type(2)));

template <int CTRL>
__device__ __forceinline__ int dpp_i(int x) {
  return __builtin_amdgcn_update_dpp(x, x, CTRL, 0xf, 0xf, false);
}

// v[lane ^ ML] on the VALU pipe. quad_perm xor1=0xB1 xor2=0x4E xor3=0x1B;
// row_half_mirror(xor7)=0x141; row_ror:8(xor8)=0x128; row_mirror(xor15)=0x140.
template <int ML>
__device__ __forceinline__ float fetchx(float v) {
  static_assert(ML >= 1 && ML < 64, "lane mask");
  int x = __float_as_int(v);
  constexpr int m4 = ML & 15;
  if constexpr (m4 == 1)       x = dpp_i<0xB1>(x);
  else if constexpr (m4 == 2)  x = dpp_i<0x4E>(x);
  else if constexpr (m4 == 3)  x = dpp_i<0x1B>(x);
  else if constexpr (m4 == 4)  { x = dpp_i<0x141>(x); x = dpp_i<0x1B>(x); }
  else if constexpr (m4 == 5)  { x = dpp_i<0x141>(x); x = dpp_i<0x4E>(x); }
  else if constexpr (m4 == 6)  { x = dpp_i<0x141>(x); x = dpp_i<0xB1>(x); }
  else if constexpr (m4 == 7)  x = dpp_i<0x141>(x);
  else if constexpr (m4 == 8)  x = dpp_i<0x128>(x);
  else if constexpr (m4 == 9)  { x = dpp_i<0x128>(x); x = dpp_i<0xB1>(x); }
  else if constexpr (m4 == 10) { x = dpp_i<0x128>(x); x = dpp_i<0x4E>(x); }
  else if constexpr (m4 == 11) { x = dpp_i<0x128>(x); x = dpp_i<0x1B>(x); }
  else if constexpr (m4 == 12) { x = dpp_i<0x140>(x); x = dpp_i<0x1B>(x); }
  else if constexpr (m4 == 13) { x = dpp_i<0x140>(x); x = dpp_i<0x4E>(x); }
  else if constexpr (m4 == 14) { x = dpp_i<0x140>(x); x = dpp_i<0xB1>(x); }
  else if constexpr (m4 == 15) x = dpp_i<0x140>(x);
  if constexpr (ML & 16) {
    v2i r = __builtin_amdgcn_permlane16_swap(x, x, false, false);
    x = (threadIdx.x & 16) ? r.x : r.y;
  }
  if constexpr (ML & 32) {
    v2i r = __builtin_amdgcn_permlane32_swap(x, x, false, false);
    x = (threadIdx.x & 32) ? r.x : r.y;
  }
  return __int_as_float(x);
}

// cur' = c*cur + sv*t where t = (partner.im, partner.re), sv = (s, -s)
__device__ __forceinline__ v2f rxup(v2f cur, float c, v2f sv, v2f t) {
  return c * cur + sv * t;        // v_pk_mul_f32 + v_pk_fma_f32
}
__device__ __forceinline__ v2f cswap(v2f a) { v2f t; t.x = a.y; t.y = a.x; return t; }
__device__ __forceinline__ v2f cmul(v2f a, v2f g) {
  v2f o; o.x = a.x * g.x - a.y * g.y; o.y = a.x * g.y + a.y * g.x; return o;
}
__device__ __forceinline__ v2f tpos(float4 g, int pos) {
  v2f t;
  if (pos) { t.x = g.w; t.y = g.z; } else { t.x = g.y; t.y = g.x; }
  return t;
}

// Generic cross-wave exchange: chunk of 4 amps (2 float4), MR <= 3.
// Alternating 8KB buffers -> 1 barrier/chunk (buffer of chunk c reused at
// c+2, whose writers passed chunk c+1's barrier, reached only after c reads).
template <int C, int WX, int ML, int MR>
__device__ __forceinline__ void xchg4(v2f (&st)[16], float c, v2f sv,
                                      float4* xbuf, int tid) {
  float4* buf = xbuf + (C & 1) * 512;
  constexpr int base = C * 4;
  buf[tid]       = make_float4(st[base+0].x, st[base+0].y, st[base+1].x, st[base+1].y);
  buf[256 + tid] = make_float4(st[base+2].x, st[base+2].y, st[base+3].x, st[base+3].y);
  __syncthreads();
  const int ptid = tid ^ ((WX << 6) | ML);
  float4 ga = buf[(0 ^ (MR >> 1)) * 256 + ptid];
  float4 gb = buf[(1 ^ (MR >> 1)) * 256 + ptid];
  constexpr int p = MR & 1;
  st[base+0] = rxup(st[base+0], c, sv, tpos(ga, p));
  st[base+1] = rxup(st[base+1], c, sv, tpos(ga, 1 - p));
  st[base+2] = rxup(st[base+2], c, sv, tpos(gb, p));
  st[base+3] = rxup(st[base+3], c, sv, tpos(gb, 1 - p));
}

// MR==7 special case (gate 44): amp r pairs with r^7 across an 8-amp window.
// Uses both buffers at once; leading+trailing barriers fence prior/next users.
template <int WX>
__device__ __forceinline__ void xchg8x7(v2f (&st)[16], float c, v2f sv,
                                        float4* xbuf, int tid) {
#pragma unroll
  for (int m = 0; m < 2; ++m) {
    const int base = m * 8;
    __syncthreads();
    xbuf[tid]       = make_float4(st[base+0].x, st[base+0].y, st[base+1].x, st[base+1].y);
    xbuf[256 + tid] = make_float4(st[base+2].x, st[base+2].y, st[base+3].x, st[base+3].y);
    xbuf[512 + tid] = make_float4(st[base+4].x, st[base+4].y, st[base+5].x, st[base+5].y);
    xbuf[768 + tid] = make_float4(st[base+6].x, st[base+6].y, st[base+7].x, st[base+7].y);
    __syncthreads();
    const int ptid = tid ^ (WX << 6);
    float4 g0 = xbuf[ptid];
    float4 g1 = xbuf[256 + ptid];
    float4 g2 = xbuf[512 + ptid];
    float4 g3 = xbuf[768 + ptid];
    st[base+0] = rxup(st[base+0], c, sv, tpos(g3, 1));
    st[base+1] = rxup(st[base+1], c, sv, tpos(g3, 0));
    st[base+2] = rxup(st[base+2], c, sv, tpos(g2, 1));
    st[base+3] = rxup(st[base+3], c, sv, tpos(g2, 0));
    st[base+4] = rxup(st[base+4], c, sv, tpos(g1, 1));
    st[base+5] = rxup(st[base+5], c, sv, tpos(g1, 0));
    st[base+6] = rxup(st[base+6], c, sv, tpos(g0, 1));
    st[base+7] = rxup(st[base+7], c, sv, tpos(g0, 0));
  }
  __syncthreads();
}

template <int G>
__device__ __forceinline__ void apply_gate(v2f (&st)[16], float c, v2f sv,
                                           float4* xbuf, int tid) {
  constexpr unsigned m = MK.rx[G];
  constexpr int wx = (int)((((m >> 11) & 1u) << 1) | (m & 1u));
  constexpr int ml = (int)((m >> 5) & 63u);
  constexpr int mr = (int)((m >> 1) & 15u);
  if constexpr (wx != 0) {
    if constexpr (mr == 7) {
      static_assert(ml == 0, "mr==7 gate must be lane-pure");
      xchg8x7<wx>(st, c, sv, xbuf, tid);
    } else {
      static_assert(mr <= 3, "partner must stay within float4 pair-chunk");
      xchg4<0, wx, ml, mr>(st, c, sv, xbuf, tid);
      xchg4<1, wx, ml, mr>(st, c, sv, xbuf, tid);
      xchg4<2, wx, ml, mr>(st, c, sv, xbuf, tid);
      xchg4<3, wx, ml, mr>(st, c, sv, xbuf, tid);
    }
  } else if constexpr (ml == 0) {
    // pure in-register pairing
#pragma unroll
    for (int r = 0; r < 16; ++r) {
      const int r2 = r ^ mr;
      if (r < r2) {
        v2f a = st[r], b = st[r2];
        st[r]  = rxup(a, c, sv, cswap(b));
        st[r2] = rxup(b, c, sv, cswap(a));
      }
    }
  } else if constexpr (mr == 0) {
    // pure cross-lane
#pragma unroll
    for (int r = 0; r < 16; ++r) {
      v2f t; t.x = fetchx<ml>(st[r].y); t.y = fetchx<ml>(st[r].x);
      st[r] = rxup(st[r], c, sv, t);
    }
  } else {
    // mixed: partner is register r^mr on lane^ml
#pragma unroll
    for (int r = 0; r < 16; ++r) {
      const int r2 = r ^ mr;
      if (r < r2) {
        v2f t1; t1.x = fetchx<ml>(st[r2].y); t1.y = fetchx<ml>(st[r2].x);
        v2f t2; t2.x = fetchx<ml>(st[r].y);  t2.y = fetchx<ml>(st[r].x);
        st[r]  = rxup(st[r],  c, sv, t1);
        st[r2] = rxup(st[r2], c, sv, t2);
      }
    }
  }
}

template <int G>
__device__ __forceinline__ void run_gates(v2f (&st)[16],
                                          const float* __restrict__ wts,
                                          float4* xbuf, int tid) {
  if constexpr (G < NGATES) {
    __builtin_amdgcn_sched_barrier(0);   // keep each gate's temps inside it
    float s, c;
    __sincosf(wts[G] * 0.5f, &s, &c);
    v2f sv; sv.x = s; sv.y = -s;
    apply_gate<G>(st, c, sv, xbuf, tid);
    run_gates<G + 1>(st, wts, xbuf, tid);
  }
}

template <int W>
__device__ __forceinline__ void expvals(const float (&a2)[16], int lane, int wv,
                                        float* zb) {
  if constexpr (W < NQ) {
    constexpr unsigned zm = MK.z[W];
    constexpr int zr  = (int)((zm >> 1) & 15u);
    constexpr int zl  = (int)((zm >> 5) & 63u);
    constexpr int zw0 = (int)(zm & 1u);
    constexpr int zw1 = (int)((zm >> 11) & 1u);
    float acc = 0.f;
#pragma unroll
    for (int r = 0; r < 16; ++r) {
      if (__builtin_popcount((unsigned)(r & zr)) & 1) acc -= a2[r];
      else                                            acc += a2[r];
    }
    const int sgn = (__popc(lane & zl) & 1) ^ (zw0 & (wv & 1)) ^
                    (zw1 & ((wv >> 1) & 1));
    if (sgn) acc = -acc;
    acc += fetchx<32>(acc);
    acc += fetchx<16>(acc);
    acc += fetchx<8>(acc);
    acc += fetchx<4>(acc);
    acc += fetchx<2>(acc);
    acc += fetchx<1>(acc);
    if (lane == 0) zb[wv * NQ + W] = acc;
    expvals<W + 1>(a2, lane, wv, zb);
  }
}

__global__ __attribute__((amdgpu_flat_work_group_size(256, 256),
                          amdgpu_waves_per_eu(4)))
void qsim_kernel(const float* __restrict__ x, const float* __restrict__ wts,
                 float* __restrict__ out) {
  __shared__ float4 xbuf[1024];        // 16 KiB exchange double-buffer
  __shared__ float zb[4 * NQ];

  const int bidx = blockIdx.x;         // one batch element per 256-thr block
  const int tid  = threadIdx.x;
  const int lane = tid & 63;
  const int wv   = tid >> 6;
  const int w0   = wv & 1;
  const int w1   = (wv >> 1) & 1;

  const float4* xv = reinterpret_cast<const float4*>(x + bidx * NQ);
  float4 q0 = xv[0], q1 = xv[1], q2 = xv[2];
  const float xa[NQ] = {q0.x, q0.y, q0.z, q0.w, q1.x, q1.y, q1.z, q1.w,
                        q2.x, q2.y, q2.z, q2.w};

  // Per-qubit factor after RY(x_w) then layer-1 RX(wts[w]):
  //   bit=0: (c*cy, -s*sy)   bit=1: (c*sy, -s*cy)
  // Scalar part: qubit 11 (bit = w0) and qubits 1..6 (lane bits 5..0).
  float lr, li;
  {
    float sy, cy, s, c;
    __sincosf(xa[11] * 0.5f, &sy, &cy);
    __sincosf(wts[11] * 0.5f, &s, &c);
    lr = w0 ? c * sy : c * cy;
    li = w0 ? -s * cy : -s * sy;
#pragma unroll
    for (int w = 1; w <= 6; ++w) {
      __sincosf(xa[w] * 0.5f, &sy, &cy);
      __sincosf(wts[w] * 0.5f, &s, &c);
      const int b = (lane >> (6 - w)) & 1;
      float gr = b ? c * sy : c * cy;
      float gi = b ? -s * cy : -s * sy;
      float nr = lr * gr - li * gi;
      float ni = lr * gi + li * gr;
      lr = nr; li = ni;
    }
  }

  // Register doubling: reg bit j (of r) = qubit 10-j, j=0..3.
  v2f st[16];
  st[0].x = lr; st[0].y = li;
#pragma unroll
  for (int j = 0; j < 4; ++j) {
    const int wq = 10 - j;
    float sy, cy, s, c;
    __sincosf(xa[wq] * 0.5f, &sy, &cy);
    __sincosf(wts[wq] * 0.5f, &s, &c);
    v2f g0; g0.x = c * cy; g0.y = -s * sy;
    v2f g1; g1.x = c * sy; g1.y = -s * cy;
#pragma unroll
    for (int k = 0; k < 16; ++k) {
      if (k < (1 << j)) {
        v2f b = st[k];
        st[k | (1 << j)] = cmul(b, g1);
        st[k]            = cmul(b, g0);
      }
    }
  }

  // Qubit 0: bit = w1 ^ par(lane) ^ par(r)  -> per-amp factor multiply.
  {
    float sy, cy, s, c;
    __sincosf(xa[0] * 0.5f, &sy, &cy);
    __sincosf(wts[0] * 0.5f, &s, &c);
    v2f F0; F0.x = c * cy; F0.y = -s * sy;
    v2f F1; F1.x = c * sy; F1.y = -s * cy;
    const int baseb = (w1 ^ __popc(lane)) & 1;
    v2f FA = baseb ? F1 : F0;
    v2f FB = baseb ? F0 : F1;
#pragma unroll
    for (int r = 0; r < 16; ++r)
      st[r] = cmul(st[r], (__builtin_popcount((unsigned)r) & 1) ? FB : FA);
  }

  run_gates<NQ>(st, wts, xbuf, tid);   // layers 2..4 (gates 12..47)
  __builtin_amdgcn_sched_barrier(0);

  float a2[16];
#pragma unroll
  for (int r = 0; r < 16; ++r) a2[r] = fmaf(st[r].x, st[r].x, st[r].y * st[r].y);

  expvals<0>(a2, lane, wv, zb);
  __syncthreads();
  if (tid < NQ)
    out[bidx * NQ + tid] = zb[tid] + zb[NQ + tid] + zb[2 * NQ + tid] + zb[3 * NQ + tid];
}

extern "C" void kernel_launch(void* const* d_in, const int* in_sizes, int n_in,
                              void* d_out, int out_size, void* d_ws, size_t ws_size,
                              hipStream_t stream) {
  const float* x   = (const float*)d_in[0];   // (4096, 12) f32
  const float* wts = (const float*)d_in[1];   // (4, 12) f32
  float* out = (float*)d_out;                 // (4096, 12) f32

  const int batch = in_sizes[0] / NQ;         // 4096
  dim3 grid(batch);
  dim3 block(256);
  qsim_kernel<<<grid, block, 0, stream>>>(x, wts, out);
}

// Round 8
// 138.293 us; speedup vs baseline: 1.0694x; 1.0409x over previous
//
#include <hip/hip_runtime.h>

#define NQ 12
#define NL 4
#define NGATES (NQ * NL)

// ---------------------------------------------------------------------------
// 256 threads per batch element; 16 amps/thread (32 VGPR state).
// Physical p (12 bits). Hardware slot coords:
//   w1 = parity(p & 0xFFE) (tid bit 7), w0 = p0 (tid bit 6),
//   lane l5..l0 = p10..p5 (tid bits 5..0), reg r3..r0 = p4..p1.
// Wave-covector pair {e0, 0xFFE} minimizes wave-crossing gates: 9 of 36.
// Gate masks covariant: m' = (parity(m&0xFFE)<<11) | (m & 0x7FF).
// Z rows contravariant:  z' = z&0x800 ? z^0x7FE : z.
// Init: qubit0 bit = w1^par(lane)^par(r); qubit11 = w0; q1..6 = lane bits;
// q7..10 = reg bits. Layer-1 RX folded into initial product state.
// Gate angles are batch-uniform: a prep kernel writes (cos,sin) for all 48
// gates to d_ws; the main kernel s_loads them (SGPR operands, no VALU trig).
// Per-thread trig (x-dependent, 12 pairs) uses native v_sin/v_cos in
// revolutions (|arg| < 0.5 rev, no range reduction needed).
// Cross-lane: DPP / permlane16/32_swap (VALU); mixed gates via ds_bpermute
// (DS pipe, idle otherwise); 9 wave-crossing gates via LDS float4 chunks.
// ---------------------------------------------------------------------------
struct Masks { unsigned rx[NGATES]; unsigned z[NQ]; };

constexpr Masks compute_masks() {
  Masks mk{};
  unsigned col[NQ] = {};
  for (int b = 0; b < NQ; ++b) col[b] = 1u << b;
  int g = 0;
  for (int l = 0; l < NL; ++l) {
    for (int w = 0; w < NQ; ++w) mk.rx[g++] = col[NQ - 1 - w];
    for (int i = 0; i < NQ; ++i) {           // ring CNOT(i, (i+1)%12)
      int cb = NQ - 1 - i;
      int tb = NQ - 1 - ((i + 1) % NQ);
      col[cb] ^= col[tb];
    }
  }
  unsigned A[NQ] = {}, Inv[NQ] = {};
  for (int i = 0; i < NQ; ++i) {
    unsigned rowv = 0;
    for (int j = 0; j < NQ; ++j) rowv |= ((col[j] >> i) & 1u) << j;
    A[i] = rowv;
    Inv[i] = 1u << i;
  }
  for (int c = 0; c < NQ; ++c) {
    int piv = c;
    while (((A[piv] >> c) & 1u) == 0u) ++piv;
    unsigned ta = A[piv]; A[piv] = A[c]; A[c] = ta;
    unsigned ti = Inv[piv]; Inv[piv] = Inv[c]; Inv[c] = ti;
    for (int r = 0; r < NQ; ++r)
      if (r != c && ((A[r] >> c) & 1u)) { A[r] ^= A[c]; Inv[r] ^= Inv[c]; }
  }
  for (int w = 0; w < NQ; ++w) mk.z[w] = Inv[NQ - 1 - w];
  for (int i = 0; i < NGATES; ++i) {
    unsigned m = mk.rx[i];
    unsigned w1 = (unsigned)(__builtin_popcount(m & 0xFFEu) & 1);
    mk.rx[i] = (w1 << 11) | (m & 0x7FFu);
  }
  for (int w = 0; w < NQ; ++w) {
    unsigned z = mk.z[w];
    mk.z[w] = (z & 0x800u) ? (z ^ 0x7FEu) : z;
  }
  return mk;
}

constexpr Masks MK = compute_masks();

typedef float v2f __attribute__((ext_vector_type(2)));
typedef int   v2i __attribute__((ext_vector_type(2)));

#define INV_2PI 0.15915494309189535f

template <int CTRL>
__device__ __forceinline__ int dpp_i(int x) {
  return __builtin_amdgcn_update_dpp(x, x, CTRL, 0xf, 0xf, false);
}

// v[lane ^ ML] on the VALU pipe. quad_perm xor1=0xB1 xor2=0x4E xor3=0x1B;
// row_half_mirror(xor7)=0x141; row_ror:8(xor8)=0x128; row_mirror(xor15)=0x140.
template <int ML>
__device__ __forceinline__ float fetchx(float v) {
  static_assert(ML >= 1 && ML < 64, "lane mask");
  int x = __float_as_int(v);
  constexpr int m4 = ML & 15;
  if constexpr (m4 == 1)       x = dpp_i<0xB1>(x);
  else if constexpr (m4 == 2)  x = dpp_i<0x4E>(x);
  else if constexpr (m4 == 3)  x = dpp_i<0x1B>(x);
  else if constexpr (m4 == 4)  { x = dpp_i<0x141>(x); x = dpp_i<0x1B>(x); }
  else if constexpr (m4 == 5)  { x = dpp_i<0x141>(x); x = dpp_i<0x4E>(x); }
  else if constexpr (m4 == 6)  { x = dpp_i<0x141>(x); x = dpp_i<0xB1>(x); }
  else if constexpr (m4 == 7)  x = dpp_i<0x141>(x);
  else if constexpr (m4 == 8)  x = dpp_i<0x128>(x);
  else if constexpr (m4 == 9)  { x = dpp_i<0x128>(x); x = dpp_i<0xB1>(x); }
  else if constexpr (m4 == 10) { x = dpp_i<0x128>(x); x = dpp_i<0x4E>(x); }
  else if constexpr (m4 == 11) { x = dpp_i<0x128>(x); x = dpp_i<0x1B>(x); }
  else if constexpr (m4 == 12) { x = dpp_i<0x140>(x); x = dpp_i<0x1B>(x); }
  else if constexpr (m4 == 13) { x = dpp_i<0x140>(x); x = dpp_i<0x4E>(x); }
  else if constexpr (m4 == 14) { x = dpp_i<0x140>(x); x = dpp_i<0xB1>(x); }
  else if constexpr (m4 == 15) x = dpp_i<0x140>(x);
  if constexpr (ML & 16) {
    v2i r = __builtin_amdgcn_permlane16_swap(x, x, false, false);
    x = (threadIdx.x & 16) ? r.x : r.y;
  }
  if constexpr (ML & 32) {
    v2i r = __builtin_amdgcn_permlane32_swap(x, x, false, false);
    x = (threadIdx.x & 32) ? r.x : r.y;
  }
  return __int_as_float(x);
}

__device__ __forceinline__ float fetch_bp(int pa, float v) {
  return __int_as_float(__builtin_amdgcn_ds_bpermute(pa, __float_as_int(v)));
}

// cur' = c*cur + sv*t where t = (partner.im, partner.re), sv = (s, -s)
__device__ __forceinline__ v2f rxup(v2f cur, float c, v2f sv, v2f t) {
  return c * cur + sv * t;        // v_pk_mul_f32 + v_pk_fma_f32
}
__device__ __forceinline__ v2f cswap(v2f a) {
  return __builtin_shufflevector(a, a, 1, 0);
}
__device__ __forceinline__ v2f cmul(v2f a, v2f g) {
  v2f o; o.x = a.x * g.x - a.y * g.y; o.y = a.x * g.y + a.y * g.x; return o;
}
__device__ __forceinline__ v2f tpos(float4 g, int pos) {
  v2f t;
  if (pos) { t.x = g.w; t.y = g.z; } else { t.x = g.y; t.y = g.x; }
  return t;
}

// Generic cross-wave exchange: chunk of 4 amps (2 float4), MR <= 3.
// Alternating 8KB buffers -> 1 barrier/chunk (buffer of chunk c reused at
// c+2, whose writers passed chunk c+1's barrier, reached only after c reads).
template <int C, int WX, int ML, int MR>
__device__ __forceinline__ void xchg4(v2f (&st)[16], float c, v2f sv,
                                      float4* xbuf, int tid) {
  float4* buf = xbuf + (C & 1) * 512;
  constexpr int base = C * 4;
  buf[tid]       = make_float4(st[base+0].x, st[base+0].y, st[base+1].x, st[base+1].y);
  buf[256 + tid] = make_float4(st[base+2].x, st[base+2].y, st[base+3].x, st[base+3].y);
  __syncthreads();
  const int ptid = tid ^ ((WX << 6) | ML);
  float4 ga = buf[(0 ^ (MR >> 1)) * 256 + ptid];
  float4 gb = buf[(1 ^ (MR >> 1)) * 256 + ptid];
  constexpr int p = MR & 1;
  st[base+0] = rxup(st[base+0], c, sv, tpos(ga, p));
  st[base+1] = rxup(st[base+1], c, sv, tpos(ga, 1 - p));
  st[base+2] = rxup(st[base+2], c, sv, tpos(gb, p));
  st[base+3] = rxup(st[base+3], c, sv, tpos(gb, 1 - p));
}

// MR==7 special case: amp r pairs with r^7 across an 8-amp window.
template <int WX>
__device__ __forceinline__ void xchg8x7(v2f (&st)[16], float c, v2f sv,
                                        float4* xbuf, int tid) {
#pragma unroll
  for (int m = 0; m < 2; ++m) {
    const int base = m * 8;
    __syncthreads();
    xbuf[tid]       = make_float4(st[base+0].x, st[base+0].y, st[base+1].x, st[base+1].y);
    xbuf[256 + tid] = make_float4(st[base+2].x, st[base+2].y, st[base+3].x, st[base+3].y);
    xbuf[512 + tid] = make_float4(st[base+4].x, st[base+4].y, st[base+5].x, st[base+5].y);
    xbuf[768 + tid] = make_float4(st[base+6].x, st[base+6].y, st[base+7].x, st[base+7].y);
    __syncthreads();
    const int ptid = tid ^ (WX << 6);
    float4 g0 = xbuf[ptid];
    float4 g1 = xbuf[256 + ptid];
    float4 g2 = xbuf[512 + ptid];
    float4 g3 = xbuf[768 + ptid];
    st[base+0] = rxup(st[base+0], c, sv, tpos(g3, 1));
    st[base+1] = rxup(st[base+1], c, sv, tpos(g3, 0));
    st[base+2] = rxup(st[base+2], c, sv, tpos(g2, 1));
    st[base+3] = rxup(st[base+3], c, sv, tpos(g2, 0));
    st[base+4] = rxup(st[base+4], c, sv, tpos(g1, 1));
    st[base+5] = rxup(st[base+5], c, sv, tpos(g1, 0));
    st[base+6] = rxup(st[base+6], c, sv, tpos(g0, 1));
    st[base+7] = rxup(st[base+7], c, sv, tpos(g0, 0));
  }
  __syncthreads();
}

template <int G>
__device__ __forceinline__ void apply_gate(v2f (&st)[16], float c, v2f sv,
                                           float4* xbuf, int tid) {
  constexpr unsigned m = MK.rx[G];
  constexpr int wx = (int)((((m >> 11) & 1u) << 1) | (m & 1u));
  constexpr int ml = (int)((m >> 5) & 63u);
  constexpr int mr = (int)((m >> 1) & 15u);
  if constexpr (wx != 0) {
    if constexpr (mr == 7) {
      static_assert(ml == 0, "mr==7 gate must be lane-pure");
      xchg8x7<wx>(st, c, sv, xbuf, tid);
    } else {
      static_assert(mr <= 3, "partner must stay within float4 pair-chunk");
      xchg4<0, wx, ml, mr>(st, c, sv, xbuf, tid);
      xchg4<1, wx, ml, mr>(st, c, sv, xbuf, tid);
      xchg4<2, wx, ml, mr>(st, c, sv, xbuf, tid);
      xchg4<3, wx, ml, mr>(st, c, sv, xbuf, tid);
    }
  } else if constexpr (ml == 0) {
    // pure in-register pairing
#pragma unroll
    for (int r = 0; r < 16; ++r) {
      const int r2 = r ^ mr;
      if (r < r2) {
        v2f a = st[r], b = st[r2];
        st[r]  = rxup(a, c, sv, cswap(b));
        st[r2] = rxup(b, c, sv, cswap(a));
      }
    }
  } else if constexpr (mr == 0) {
    // pure cross-lane: VALU (DPP/permlane)
#pragma unroll
    for (int r = 0; r < 16; ++r) {
      v2f t; t.x = fetchx<ml>(st[r].y); t.y = fetchx<ml>(st[r].x);
      st[r] = rxup(st[r], c, sv, t);
    }
  } else {
    // mixed: partner is register r^mr on lane^ml -> DS pipe (ds_bpermute),
    // address hoisted once per gate; VALU only does the pk math.
    const int pa = ((tid & 63) ^ ml) << 2;
#pragma unroll
    for (int r = 0; r < 16; ++r) {
      const int r2 = r ^ mr;
      if (r < r2) {
        v2f t1; t1.x = fetch_bp(pa, st[r2].y); t1.y = fetch_bp(pa, st[r2].x);
        v2f t2; t2.x = fetch_bp(pa, st[r].y);  t2.y = fetch_bp(pa, st[r].x);
        st[r]  = rxup(st[r],  c, sv, t1);
        st[r2] = rxup(st[r2], c, sv, t2);
      }
    }
  }
}

template <int G>
__device__ __forceinline__ void run_gates(v2f (&st)[16],
                                          const float2* __restrict__ tab,
                                          float4* xbuf, int tid) {
  if constexpr (G < NGATES) {
    const float2 cs = tab[G];        // uniform -> s_load, SGPR operands
    v2f sv; sv.x = cs.y; sv.y = -cs.y;
    apply_gate<G>(st, cs.x, sv, xbuf, tid);
    run_gates<G + 1>(st, tab, xbuf, tid);
  }
}

template <int W>
__device__ __forceinline__ void expvals(const float (&a2)[16], int lane, int wv,
                                        float* zb) {
  if constexpr (W < NQ) {
    constexpr unsigned zm = MK.z[W];
    constexpr int zr  = (int)((zm >> 1) & 15u);
    constexpr int zl  = (int)((zm >> 5) & 63u);
    constexpr int zw0 = (int)(zm & 1u);
    constexpr int zw1 = (int)((zm >> 11) & 1u);
    float acc = 0.f;
#pragma unroll
    for (int r = 0; r < 16; ++r) {
      if (__builtin_popcount((unsigned)(r & zr)) & 1) acc -= a2[r];
      else                                            acc += a2[r];
    }
    const int sgn = (__popc(lane & zl) & 1) ^ (zw0 & (wv & 1)) ^
                    (zw1 & ((wv >> 1) & 1));
    if (sgn) acc = -acc;
    // permlane swap: self + partner without select
    {
      v2i r = __builtin_amdgcn_permlane32_swap(__float_as_int(acc),
                                               __float_as_int(acc), false, false);
      acc = __int_as_float(r.x) + __int_as_float(r.y);
    }
    {
      v2i r = __builtin_amdgcn_permlane16_swap(__float_as_int(acc),
                                               __float_as_int(acc), false, false);
      acc = __int_as_float(r.x) + __int_as_float(r.y);
    }
    acc += fetchx<8>(acc);
    acc += fetchx<4>(acc);
    acc += fetchx<2>(acc);
    acc += fetchx<1>(acc);
    if (lane == 0) zb[wv * NQ + W] = acc;
    expvals<W + 1>(a2, lane, wv, zb);
  }
}

// Prep: 48 batch-uniform gate angles -> (cos, sin) table in d_ws.
__global__ void prep_kernel(const float* __restrict__ wts,
                            float2* __restrict__ tab) {
  const int i = threadIdx.x;
  if (i < NGATES) {
    float s, c;
    __sincosf(wts[i] * 0.5f, &s, &c);
    tab[i] = make_float2(c, s);
  }
}

__global__ __attribute__((amdgpu_flat_work_group_size(256, 256),
                          amdgpu_waves_per_eu(8)))
void qsim_kernel(const float* __restrict__ x,
                 const float2* __restrict__ tab,
                 float* __restrict__ out) {
  __shared__ float4 xbuf[1024];        // 16 KiB exchange double-buffer
  __shared__ float zb[4 * NQ];

  const int bidx = blockIdx.x;         // one batch element per 256-thr block
  const int tid  = threadIdx.x;
  const int lane = tid & 63;
  const int wv   = tid >> 6;
  const int w0   = wv & 1;
  const int w1   = (wv >> 1) & 1;

  const float4* xv = reinterpret_cast<const float4*>(x + bidx * NQ);
  float4 q0 = xv[0], q1 = xv[1], q2 = xv[2];
  const float xa[NQ] = {q0.x, q0.y, q0.z, q0.w, q1.x, q1.y, q1.z, q1.w,
                        q2.x, q2.y, q2.z, q2.w};

  // Per-qubit factor after RY(x_w) then layer-1 RX(wts[w]):
  //   bit=0: (c*cy, -s*sy)   bit=1: (c*sy, -s*cy)
  // RY trig: native sin/cos in revolutions (|arg| < 0.5 rev).
  // Scalar part: qubit 11 (bit = w0) and qubits 1..6 (lane bits 5..0).
  float lr, li;
  {
    float rv = xa[11] * (0.5f * INV_2PI);
    float sy = __builtin_amdgcn_sinf(rv), cy = __builtin_amdgcn_cosf(rv);
    const float2 cs = tab[11];
    lr = w0 ? cs.x * sy : cs.x * cy;
    li = w0 ? -cs.y * cy : -cs.y * sy;
#pragma unroll
    for (int w = 1; w <= 6; ++w) {
      rv = xa[w] * (0.5f * INV_2PI);
      sy = __builtin_amdgcn_sinf(rv); cy = __builtin_amdgcn_cosf(rv);
      const float2 g = tab[w];
      const int b = (lane >> (6 - w)) & 1;
      float gr = b ? g.x * sy : g.x * cy;
      float gi = b ? -g.y * cy : -g.y * sy;
      float nr = lr * gr - li * gi;
      float ni = lr * gi + li * gr;
      lr = nr; li = ni;
    }
  }

  // Register doubling: reg bit j (of r) = qubit 10-j, j=0..3.
  v2f st[16];
  st[0].x = lr; st[0].y = li;
#pragma unroll
  for (int j = 0; j < 4; ++j) {
    const int wq = 10 - j;
    float rv = xa[wq] * (0.5f * INV_2PI);
    float sy = __builtin_amdgcn_sinf(rv), cy = __builtin_amdgcn_cosf(rv);
    const float2 cs = tab[wq];
    v2f g0; g0.x = cs.x * cy; g0.y = -cs.y * sy;
    v2f g1; g1.x = cs.x * sy; g1.y = -cs.y * cy;
#pragma unroll
    for (int k = 0; k < 16; ++k) {
      if (k < (1 << j)) {
        v2f b = st[k];
        st[k | (1 << j)] = cmul(b, g1);
        st[k]            = cmul(b, g0);
      }
    }
  }

  // Qubit 0: bit = w1 ^ par(lane) ^ par(r)  -> per-amp factor multiply.
  {
    float rv = xa[0] * (0.5f * INV_2PI);
    float sy = __builtin_amdgcn_sinf(rv), cy = __builtin_amdgcn_cosf(rv);
    const float2 cs = tab[0];
    v2f F0; F0.x = cs.x * cy; F0.y = -cs.y * sy;
    v2f F1; F1.x = cs.x * sy; F1.y = -cs.y * cy;
    const int baseb = (w1 ^ __popc(lane)) & 1;
    v2f FA = baseb ? F1 : F0;
    v2f FB = baseb ? F0 : F1;
#pragma unroll
    for (int r = 0; r < 16; ++r)
      st[r] = cmul(st[r], (__builtin_popcount((unsigned)r) & 1) ? FB : FA);
  }

  run_gates<NQ>(st, tab, xbuf, tid);   // layers 2..4 (gates 12..47)

  float a2[16];
#pragma unroll
  for (int r = 0; r < 16; ++r) a2[r] = fmaf(st[r].x, st[r].x, st[r].y * st[r].y);

  expvals<0>(a2, lane, wv, zb);
  __syncthreads();
  if (tid < NQ)
    out[bidx * NQ + tid] = zb[tid] + zb[NQ + tid] + zb[2 * NQ + tid] + zb[3 * NQ + tid];
}

extern "C" void kernel_launch(void* const* d_in, const int* in_sizes, int n_in,
                              void* d_out, int out_size, void* d_ws, size_t ws_size,
                              hipStream_t stream) {
  const float* x   = (const float*)d_in[0];   // (4096, 12) f32
  const float* wts = (const float*)d_in[1];   // (4, 12) f32
  float* out = (float*)d_out;                 // (4096, 12) f32
  float2* tab = (float2*)d_ws;                // 48 * 8 B gate table

  prep_kernel<<<1, 64, 0, stream>>>(wts, tab);

  const int batch = in_sizes[0] / NQ;         // 4096
  dim3 grid(batch);
  dim3 block(256);
  qsim_kernel<<<grid, block, 0, stream>>>(x, tab, out);
}

// Round 9
// 137.134 us; speedup vs baseline: 1.0784x; 1.0084x over previous
//
#include <hip/hip_runtime.h>

#define NQ 12
#define NL 4
#define NGATES (NQ * NL)

// ---------------------------------------------------------------------------
// 256 threads per batch element; 16 amps/thread (32 VGPR state).
// Physical p (12 bits). Hardware slot coords:
//   w1 = parity(p & 0xFFE) (tid bit 7), w0 = p0 (tid bit 6),
//   lane l5..l0 = p10..p5 (tid bits 5..0), reg r3..r0 = p4..p1.
// Wave-covector pair {e0, 0xFFE} minimizes wave-crossing gates: 9 of 36.
// Gate masks covariant: m' = (parity(m&0xFFE)<<11) | (m & 0x7FF).
// Z rows contravariant:  z' = z&0x800 ? z^0x7FE : z.
// Init: qubit0 bit = w1^par(lane)^par(r); qubit11 = w0; q1..6 = lane bits;
// q7..10 = reg bits. Layer-1 RX folded into initial product state.
// Gate angles are batch-uniform: a prep kernel writes (cos,sin) for all 48
// gates to d_ws; the main kernel s_loads them (SGPR operands, no VALU trig).
// Per-thread trig (x-dependent, 12 pairs) uses native v_sin/v_cos in
// revolutions (|arg| < 0.5 rev, no range reduction needed).
// Cross-lane: DPP / permlane16/32_swap (VALU); mixed gates via ds_bpermute
// (DS pipe, idle otherwise); 9 wave-crossing gates via LDS float4 chunks.
// waves_per_eu(4): 128-reg budget. (8) was tried in round 8: the 64-reg cap
// spilled ~25 floats/thread -> 42 MB scratch writes. (4) fits demand (~40).
// ---------------------------------------------------------------------------
struct Masks { unsigned rx[NGATES]; unsigned z[NQ]; };

constexpr Masks compute_masks() {
  Masks mk{};
  unsigned col[NQ] = {};
  for (int b = 0; b < NQ; ++b) col[b] = 1u << b;
  int g = 0;
  for (int l = 0; l < NL; ++l) {
    for (int w = 0; w < NQ; ++w) mk.rx[g++] = col[NQ - 1 - w];
    for (int i = 0; i < NQ; ++i) {           // ring CNOT(i, (i+1)%12)
      int cb = NQ - 1 - i;
      int tb = NQ - 1 - ((i + 1) % NQ);
      col[cb] ^= col[tb];
    }
  }
  unsigned A[NQ] = {}, Inv[NQ] = {};
  for (int i = 0; i < NQ; ++i) {
    unsigned rowv = 0;
    for (int j = 0; j < NQ; ++j) rowv |= ((col[j] >> i) & 1u) << j;
    A[i] = rowv;
    Inv[i] = 1u << i;
  }
  for (int c = 0; c < NQ; ++c) {
    int piv = c;
    while (((A[piv] >> c) & 1u) == 0u) ++piv;
    unsigned ta = A[piv]; A[piv] = A[c]; A[c] = ta;
    unsigned ti = Inv[piv]; Inv[piv] = Inv[c]; Inv[c] = ti;
    for (int r = 0; r < NQ; ++r)
      if (r != c && ((A[r] >> c) & 1u)) { A[r] ^= A[c]; Inv[r] ^= Inv[c]; }
  }
  for (int w = 0; w < NQ; ++w) mk.z[w] = Inv[NQ - 1 - w];
  for (int i = 0; i < NGATES; ++i) {
    unsigned m = mk.rx[i];
    unsigned w1 = (unsigned)(__builtin_popcount(m & 0xFFEu) & 1);
    mk.rx[i] = (w1 << 11) | (m & 0x7FFu);
  }
  for (int w = 0; w < NQ; ++w) {
    unsigned z = mk.z[w];
    mk.z[w] = (z & 0x800u) ? (z ^ 0x7FEu) : z;
  }
  return mk;
}

constexpr Masks MK = compute_masks();

typedef float v2f __attribute__((ext_vector_type(2)));
typedef int   v2i __attribute__((ext_vector_type(2)));

#define INV_2PI 0.15915494309189535f

template <int CTRL>
__device__ __forceinline__ int dpp_i(int x) {
  return __builtin_amdgcn_update_dpp(x, x, CTRL, 0xf, 0xf, false);
}

// v[lane ^ ML] on the VALU pipe. quad_perm xor1=0xB1 xor2=0x4E xor3=0x1B;
// row_half_mirror(xor7)=0x141; row_ror:8(xor8)=0x128; row_mirror(xor15)=0x140.
template <int ML>
__device__ __forceinline__ float fetchx(float v) {
  static_assert(ML >= 1 && ML < 64, "lane mask");
  int x = __float_as_int(v);
  constexpr int m4 = ML & 15;
  if constexpr (m4 == 1)       x = dpp_i<0xB1>(x);
  else if constexpr (m4 == 2)  x = dpp_i<0x4E>(x);
  else if constexpr (m4 == 3)  x = dpp_i<0x1B>(x);
  else if constexpr (m4 == 4)  { x = dpp_i<0x141>(x); x = dpp_i<0x1B>(x); }
  else if constexpr (m4 == 5)  { x = dpp_i<0x141>(x); x = dpp_i<0x4E>(x); }
  else if constexpr (m4 == 6)  { x = dpp_i<0x141>(x); x = dpp_i<0xB1>(x); }
  else if constexpr (m4 == 7)  x = dpp_i<0x141>(x);
  else if constexpr (m4 == 8)  x = dpp_i<0x128>(x);
  else if constexpr (m4 == 9)  { x = dpp_i<0x128>(x); x = dpp_i<0xB1>(x); }
  else if constexpr (m4 == 10) { x = dpp_i<0x128>(x); x = dpp_i<0x4E>(x); }
  else if constexpr (m4 == 11) { x = dpp_i<0x128>(x); x = dpp_i<0x1B>(x); }
  else if constexpr (m4 == 12) { x = dpp_i<0x140>(x); x = dpp_i<0x1B>(x); }
  else if constexpr (m4 == 13) { x = dpp_i<0x140>(x); x = dpp_i<0x4E>(x); }
  else if constexpr (m4 == 14) { x = dpp_i<0x140>(x); x = dpp_i<0xB1>(x); }
  else if constexpr (m4 == 15) x = dpp_i<0x140>(x);
  if constexpr (ML & 16) {
    v2i r = __builtin_amdgcn_permlane16_swap(x, x, false, false);
    x = (threadIdx.x & 16) ? r.x : r.y;
  }
  if constexpr (ML & 32) {
    v2i r = __builtin_amdgcn_permlane32_swap(x, x, false, false);
    x = (threadIdx.x & 32) ? r.x : r.y;
  }
  return __int_as_float(x);
}

__device__ __forceinline__ float fetch_bp(int pa, float v) {
  return __int_as_float(__builtin_amdgcn_ds_bpermute(pa, __float_as_int(v)));
}

// cur' = c*cur + sv*t where t = (partner.im, partner.re), sv = (s, -s)
__device__ __forceinline__ v2f rxup(v2f cur, float c, v2f sv, v2f t) {
  return c * cur + sv * t;        // v_pk_mul_f32 + v_pk_fma_f32
}
__device__ __forceinline__ v2f cswap(v2f a) {
  return __builtin_shufflevector(a, a, 1, 0);
}
__device__ __forceinline__ v2f cmul(v2f a, v2f g) {
  v2f o; o.x = a.x * g.x - a.y * g.y; o.y = a.x * g.y + a.y * g.x; return o;
}
__device__ __forceinline__ v2f tpos(float4 g, int pos) {
  v2f t;
  if (pos) { t.x = g.w; t.y = g.z; } else { t.x = g.y; t.y = g.x; }
  return t;
}

// Generic cross-wave exchange: chunk of 4 amps (2 float4), MR <= 3.
// Alternating 8KB buffers -> 1 barrier/chunk (buffer of chunk c reused at
// c+2, whose writers passed chunk c+1's barrier, reached only after c reads).
template <int C, int WX, int ML, int MR>
__device__ __forceinline__ void xchg4(v2f (&st)[16], float c, v2f sv,
                                      float4* xbuf, int tid) {
  float4* buf = xbuf + (C & 1) * 512;
  constexpr int base = C * 4;
  buf[tid]       = make_float4(st[base+0].x, st[base+0].y, st[base+1].x, st[base+1].y);
  buf[256 + tid] = make_float4(st[base+2].x, st[base+2].y, st[base+3].x, st[base+3].y);
  __syncthreads();
  const int ptid = tid ^ ((WX << 6) | ML);
  float4 ga = buf[(0 ^ (MR >> 1)) * 256 + ptid];
  float4 gb = buf[(1 ^ (MR >> 1)) * 256 + ptid];
  constexpr int p = MR & 1;
  st[base+0] = rxup(st[base+0], c, sv, tpos(ga, p));
  st[base+1] = rxup(st[base+1], c, sv, tpos(ga, 1 - p));
  st[base+2] = rxup(st[base+2], c, sv, tpos(gb, p));
  st[base+3] = rxup(st[base+3], c, sv, tpos(gb, 1 - p));
}

// MR==7 special case: amp r pairs with r^7 across an 8-amp window.
template <int WX>
__device__ __forceinline__ void xchg8x7(v2f (&st)[16], float c, v2f sv,
                                        float4* xbuf, int tid) {
#pragma unroll
  for (int m = 0; m < 2; ++m) {
    const int base = m * 8;
    __syncthreads();
    xbuf[tid]       = make_float4(st[base+0].x, st[base+0].y, st[base+1].x, st[base+1].y);
    xbuf[256 + tid] = make_float4(st[base+2].x, st[base+2].y, st[base+3].x, st[base+3].y);
    xbuf[512 + tid] = make_float4(st[base+4].x, st[base+4].y, st[base+5].x, st[base+5].y);
    xbuf[768 + tid] = make_float4(st[base+6].x, st[base+6].y, st[base+7].x, st[base+7].y);
    __syncthreads();
    const int ptid = tid ^ (WX << 6);
    float4 g0 = xbuf[ptid];
    float4 g1 = xbuf[256 + ptid];
    float4 g2 = xbuf[512 + ptid];
    float4 g3 = xbuf[768 + ptid];
    st[base+0] = rxup(st[base+0], c, sv, tpos(g3, 1));
    st[base+1] = rxup(st[base+1], c, sv, tpos(g3, 0));
    st[base+2] = rxup(st[base+2], c, sv, tpos(g2, 1));
    st[base+3] = rxup(st[base+3], c, sv, tpos(g2, 0));
    st[base+4] = rxup(st[base+4], c, sv, tpos(g1, 1));
    st[base+5] = rxup(st[base+5], c, sv, tpos(g1, 0));
    st[base+6] = rxup(st[base+6], c, sv, tpos(g0, 1));
    st[base+7] = rxup(st[base+7], c, sv, tpos(g0, 0));
  }
  __syncthreads();
}

template <int G>
__device__ __forceinline__ void apply_gate(v2f (&st)[16], float c, v2f sv,
                                           float4* xbuf, int tid) {
  constexpr unsigned m = MK.rx[G];
  constexpr int wx = (int)((((m >> 11) & 1u) << 1) | (m & 1u));
  constexpr int ml = (int)((m >> 5) & 63u);
  constexpr int mr = (int)((m >> 1) & 15u);
  if constexpr (wx != 0) {
    if constexpr (mr == 7) {
      static_assert(ml == 0, "mr==7 gate must be lane-pure");
      xchg8x7<wx>(st, c, sv, xbuf, tid);
    } else {
      static_assert(mr <= 3, "partner must stay within float4 pair-chunk");
      xchg4<0, wx, ml, mr>(st, c, sv, xbuf, tid);
      xchg4<1, wx, ml, mr>(st, c, sv, xbuf, tid);
      xchg4<2, wx, ml, mr>(st, c, sv, xbuf, tid);
      xchg4<3, wx, ml, mr>(st, c, sv, xbuf, tid);
    }
  } else if constexpr (ml == 0) {
    // pure in-register pairing
#pragma unroll
    for (int r = 0; r < 16; ++r) {
      const int r2 = r ^ mr;
      if (r < r2) {
        v2f a = st[r], b = st[r2];
        st[r]  = rxup(a, c, sv, cswap(b));
        st[r2] = rxup(b, c, sv, cswap(a));
      }
    }
  } else if constexpr (mr == 0) {
    // pure cross-lane: VALU (DPP/permlane)
#pragma unroll
    for (int r = 0; r < 16; ++r) {
      v2f t; t.x = fetchx<ml>(st[r].y); t.y = fetchx<ml>(st[r].x);
      st[r] = rxup(st[r], c, sv, t);
    }
  } else {
    // mixed: partner is register r^mr on lane^ml -> DS pipe (ds_bpermute),
    // address hoisted once per gate; VALU only does the pk math.
    const int pa = ((tid & 63) ^ ml) << 2;
#pragma unroll
    for (int r = 0; r < 16; ++r) {
      const int r2 = r ^ mr;
      if (r < r2) {
        v2f t1; t1.x = fetch_bp(pa, st[r2].y); t1.y = fetch_bp(pa, st[r2].x);
        v2f t2; t2.x = fetch_bp(pa, st[r].y);  t2.y = fetch_bp(pa, st[r].x);
        st[r]  = rxup(st[r],  c, sv, t1);
        st[r2] = rxup(st[r2], c, sv, t2);
      }
    }
  }
}

template <int G>
__device__ __forceinline__ void run_gates(v2f (&st)[16],
                                          const float2* __restrict__ tab,
                                          float4* xbuf, int tid) {
  if constexpr (G < NGATES) {
    const float2 cs = tab[G];        // uniform -> s_load, SGPR operands
    v2f sv; sv.x = cs.y; sv.y = -cs.y;
    apply_gate<G>(st, cs.x, sv, xbuf, tid);
    run_gates<G + 1>(st, tab, xbuf, tid);
  }
}

template <int W>
__device__ __forceinline__ void expvals(const float (&a2)[16], int lane, int wv,
                                        float* zb) {
  if constexpr (W < NQ) {
    constexpr unsigned zm = MK.z[W];
    constexpr int zr  = (int)((zm >> 1) & 15u);
    constexpr int zl  = (int)((zm >> 5) & 63u);
    constexpr int zw0 = (int)(zm & 1u);
    constexpr int zw1 = (int)((zm >> 11) & 1u);
    float acc = 0.f;
#pragma unroll
    for (int r = 0; r < 16; ++r) {
      if (__builtin_popcount((unsigned)(r & zr)) & 1) acc -= a2[r];
      else                                            acc += a2[r];
    }
    const int sgn = (__popc(lane & zl) & 1) ^ (zw0 & (wv & 1)) ^
                    (zw1 & ((wv >> 1) & 1));
    if (sgn) acc = -acc;
    // permlane swap: self + partner without select
    {
      v2i r = __builtin_amdgcn_permlane32_swap(__float_as_int(acc),
                                               __float_as_int(acc), false, false);
      acc = __int_as_float(r.x) + __int_as_float(r.y);
    }
    {
      v2i r = __builtin_amdgcn_permlane16_swap(__float_as_int(acc),
                                               __float_as_int(acc), false, false);
      acc = __int_as_float(r.x) + __int_as_float(r.y);
    }
    acc += fetchx<8>(acc);
    acc += fetchx<4>(acc);
    acc += fetchx<2>(acc);
    acc += fetchx<1>(acc);
    if (lane == 0) zb[wv * NQ + W] = acc;
    expvals<W + 1>(a2, lane, wv, zb);
  }
}

// Prep: 48 batch-uniform gate angles -> (cos, sin) table in d_ws.
__global__ void prep_kernel(const float* __restrict__ wts,
                            float2* __restrict__ tab) {
  const int i = threadIdx.x;
  if (i < NGATES) {
    float s, c;
    __sincosf(wts[i] * 0.5f, &s, &c);
    tab[i] = make_float2(c, s);
  }
}

__global__ __attribute__((amdgpu_flat_work_group_size(256, 256),
                          amdgpu_waves_per_eu(4)))
void qsim_kernel(const float* __restrict__ x,
                 const float2* __restrict__ tab,
                 float* __restrict__ out) {
  __shared__ float4 xbuf[1024];        // 16 KiB exchange double-buffer
  __shared__ float zb[4 * NQ];

  const int bidx = blockIdx.x;         // one batch element per 256-thr block
  const int tid  = threadIdx.x;
  const int lane = tid & 63;
  const int wv   = tid >> 6;
  const int w0   = wv & 1;
  const int w1   = (wv >> 1) & 1;

  const float4* xv = reinterpret_cast<const float4*>(x + bidx * NQ);
  float4 q0 = xv[0], q1 = xv[1], q2 = xv[2];
  const float xa[NQ] = {q0.x, q0.y, q0.z, q0.w, q1.x, q1.y, q1.z, q1.w,
                        q2.x, q2.y, q2.z, q2.w};

  // Per-qubit factor after RY(x_w) then layer-1 RX(wts[w]):
  //   bit=0: (c*cy, -s*sy)   bit=1: (c*sy, -s*cy)
  // RY trig: native sin/cos in revolutions (|arg| < 0.5 rev).
  // Scalar part: qubit 11 (bit = w0) and qubits 1..6 (lane bits 5..0).
  float lr, li;
  {
    float rv = xa[11] * (0.5f * INV_2PI);
    float sy = __builtin_amdgcn_sinf(rv), cy = __builtin_amdgcn_cosf(rv);
    const float2 cs = tab[11];
    lr = w0 ? cs.x * sy : cs.x * cy;
    li = w0 ? -cs.y * cy : -cs.y * sy;
#pragma unroll
    for (int w = 1; w <= 6; ++w) {
      rv = xa[w] * (0.5f * INV_2PI);
      sy = __builtin_amdgcn_sinf(rv); cy = __builtin_amdgcn_cosf(rv);
      const float2 g = tab[w];
      const int b = (lane >> (6 - w)) & 1;
      float gr = b ? g.x * sy : g.x * cy;
      float gi = b ? -g.y * cy : -g.y * sy;
      float nr = lr * gr - li * gi;
      float ni = lr * gi + li * gr;
      lr = nr; li = ni;
    }
  }

  // Register doubling: reg bit j (of r) = qubit 10-j, j=0..3.
  v2f st[16];
  st[0].x = lr; st[0].y = li;
#pragma unroll
  for (int j = 0; j < 4; ++j) {
    const int wq = 10 - j;
    float rv = xa[wq] * (0.5f * INV_2PI);
    float sy = __builtin_amdgcn_sinf(rv), cy = __builtin_amdgcn_cosf(rv);
    const float2 cs = tab[wq];
    v2f g0; g0.x = cs.x * cy; g0.y = -cs.y * sy;
    v2f g1; g1.x = cs.x * sy; g1.y = -cs.y * cy;
#pragma unroll
    for (int k = 0; k < 16; ++k) {
      if (k < (1 << j)) {
        v2f b = st[k];
        st[k | (1 << j)] = cmul(b, g1);
        st[k]            = cmul(b, g0);
      }
    }
  }

  // Qubit 0: bit = w1 ^ par(lane) ^ par(r)  -> per-amp factor multiply.
  {
    float rv = xa[0] * (0.5f * INV_2PI);
    float sy = __builtin_amdgcn_sinf(rv), cy = __builtin_amdgcn_cosf(rv);
    const float2 cs = tab[0];
    v2f F0; F0.x = cs.x * cy; F0.y = -cs.y * sy;
    v2f F1; F1.x = cs.x * sy; F1.y = -cs.y * cy;
    const int baseb = (w1 ^ __popc(lane)) & 1;
    v2f FA = baseb ? F1 : F0;
    v2f FB = baseb ? F0 : F1;
#pragma unroll
    for (int r = 0; r < 16; ++r)
      st[r] = cmul(st[r], (__builtin_popcount((unsigned)r) & 1) ? FB : FA);
  }

  run_gates<NQ>(st, tab, xbuf, tid);   // layers 2..4 (gates 12..47)

  float a2[16];
#pragma unroll
  for (int r = 0; r < 16; ++r) a2[r] = fmaf(st[r].x, st[r].x, st[r].y * st[r].y);

  expvals<0>(a2, lane, wv, zb);
  __syncthreads();
  if (tid < NQ)
    out[bidx * NQ + tid] = zb[tid] + zb[NQ + tid] + zb[2 * NQ + tid] + zb[3 * NQ + tid];
}

extern "C" void kernel_launch(void* const* d_in, const int* in_sizes, int n_in,
                              void* d_out, int out_size, void* d_ws, size_t ws_size,
                              hipStream_t stream) {
  const float* x   = (const float*)d_in[0];   // (4096, 12) f32
  const float* wts = (const float*)d_in[1];   // (4, 12) f32
  float* out = (float*)d_out;                 // (4096, 12) f32
  float2* tab = (float2*)d_ws;                // 48 * 8 B gate table

  prep_kernel<<<1, 64, 0, stream>>>(wts, tab);

  const int batch = in_sizes[0] / NQ;         // 4096
  dim3 grid(batch);
  dim3 block(256);
  qsim_kernel<<<grid, block, 0, stream>>>(x, tab, out);
}

// Round 10
// 104.405 us; speedup vs baseline: 1.4164x; 1.3135x over previous
//
#include <hip/hip_runtime.h>

#define NQ 12
#define NL 4
#define NGATES (NQ * NL)

// ---------------------------------------------------------------------------
// 128 threads per batch element; 32 amps/thread (64 VGPR state), 2 waves.
// GF(2) chain basis: b_k = {k,k+1} (k=0..10), b11 = {11}. Slot coords y:
//   y_j = parity(p & ((2<<j)-1)) for j<=10,  y11 = parity(p).
//   reg r = y0..y4 (32 amps), lane = y5..y10, wave = y11 (tid bit 6).
// Mask m's image = same prefix-parity transform (ytrans). Consequence:
//   {k,k+1} -> single coord bit; {k,k+2} -> 2 adjacent bits; {k..k+3} ->
//   bits k,k+2. So: 12 gates REG-PURE, 11 lane gates 1-2 DPP, 4+1 gates
//   ds_bpermute, and only FIVE wave-crossing (LDS) gates (parity-odd masks).
// Z rows contravariant: zeta_k = z_k^z_{k+1}, zeta11 = z11 (ztrans).
// Init: p0 = r0, p_j = r_{j-1}^r_j (j=1..4), p5 = r4^l0, p_{5+i} = l_{i-1}^l_i,
// p11 = l5^wv. Product state built by y-space doubling with compile-time
// neighbor bits; layer-1 RX folded in. Gate angles batch-uniform -> prep
// kernel writes (cos,sin) to d_ws, main kernel s_loads (SGPR operands).
// LDS exchange: ds b64 (v2f direct), chunk pairs (0,3),(1,2), 16KB dbuf.
// ---------------------------------------------------------------------------
struct Masks { unsigned rx[NGATES]; unsigned z[NQ]; };

constexpr unsigned ytrans(unsigned m) {   // covariant: coords of m in chain basis
  unsigned e = 0;
  for (int j = 0; j <= 10; ++j)
    e |= (unsigned)(__builtin_popcount(m & ((2u << j) - 1u)) & 1) << j;
  e |= (unsigned)(__builtin_popcount(m & 0xFFFu) & 1) << 11;
  return e;
}
constexpr unsigned ztrans(unsigned z) {   // contravariant: zeta_i = z . b_i
  unsigned e = 0;
  for (int j = 0; j <= 10; ++j) e |= (((z >> j) ^ (z >> (j + 1))) & 1u) << j;
  e |= ((z >> 11) & 1u) << 11;
  return e;
}

constexpr Masks compute_masks() {
  Masks mk{};
  unsigned col[NQ] = {};
  for (int b = 0; b < NQ; ++b) col[b] = 1u << b;
  int g = 0;
  for (int l = 0; l < NL; ++l) {
    for (int w = 0; w < NQ; ++w) mk.rx[g++] = col[NQ - 1 - w];
    for (int i = 0; i < NQ; ++i) {           // ring CNOT(i, (i+1)%12)
      int cb = NQ - 1 - i;
      int tb = NQ - 1 - ((i + 1) % NQ);
      col[cb] ^= col[tb];
    }
  }
  unsigned A[NQ] = {}, Inv[NQ] = {};
  for (int i = 0; i < NQ; ++i) {
    unsigned rowv = 0;
    for (int j = 0; j < NQ; ++j) rowv |= ((col[j] >> i) & 1u) << j;
    A[i] = rowv;
    Inv[i] = 1u << i;
  }
  for (int c = 0; c < NQ; ++c) {
    int piv = c;
    while (((A[piv] >> c) & 1u) == 0u) ++piv;
    unsigned ta = A[piv]; A[piv] = A[c]; A[c] = ta;
    unsigned ti = Inv[piv]; Inv[piv] = Inv[c]; Inv[c] = ti;
    for (int r = 0; r < NQ; ++r)
      if (r != c && ((A[r] >> c) & 1u)) { A[r] ^= A[c]; Inv[r] ^= Inv[c]; }
  }
  for (int w = 0; w < NQ; ++w) mk.z[w] = ztrans(Inv[NQ - 1 - w]);
  for (int i = 0; i < NGATES; ++i) mk.rx[i] = ytrans(mk.rx[i]);
  return mk;
}

constexpr Masks MK = compute_masks();

typedef float v2f __attribute__((ext_vector_type(2)));
typedef int   v2i __attribute__((ext_vector_type(2)));

#define INV_2PI 0.15915494309189535f

template <int CTRL>
__device__ __forceinline__ int dpp_i(int x) {
  return __builtin_amdgcn_update_dpp(x, x, CTRL, 0xf, 0xf, false);
}

// VALU cost of a cross-lane xor-mask fetch (DPP/permlane path).
constexpr int dppcost(int ml) {
  int m4 = ml & 15;
  int c = (m4 == 0) ? 0
        : ((m4 == 1 || m4 == 2 || m4 == 3 || m4 == 7 || m4 == 8 || m4 == 15) ? 1 : 2);
  if (ml & 16) c += 2;
  if (ml & 32) c += 2;
  return c;
}

// v[lane ^ ML] on the VALU pipe. quad_perm xor1=0xB1 xor2=0x4E xor3=0x1B;
// row_half_mirror(xor7)=0x141; row_ror:8(xor8)=0x128; row_mirror(xor15)=0x140.
template <int ML>
__device__ __forceinline__ float fetchx(float v) {
  static_assert(ML >= 1 && ML < 64, "lane mask");
  int x = __float_as_int(v);
  constexpr int m4 = ML & 15;
  if constexpr (m4 == 1)       x = dpp_i<0xB1>(x);
  else if constexpr (m4 == 2)  x = dpp_i<0x4E>(x);
  else if constexpr (m4 == 3)  x = dpp_i<0x1B>(x);
  else if constexpr (m4 == 4)  { x = dpp_i<0x141>(x); x = dpp_i<0x1B>(x); }
  else if constexpr (m4 == 5)  { x = dpp_i<0x141>(x); x = dpp_i<0x4E>(x); }
  else if constexpr (m4 == 6)  { x = dpp_i<0x141>(x); x = dpp_i<0xB1>(x); }
  else if constexpr (m4 == 7)  x = dpp_i<0x141>(x);
  else if constexpr (m4 == 8)  x = dpp_i<0x128>(x);
  else if constexpr (m4 == 9)  { x = dpp_i<0x128>(x); x = dpp_i<0xB1>(x); }
  else if constexpr (m4 == 10) { x = dpp_i<0x128>(x); x = dpp_i<0x4E>(x); }
  else if constexpr (m4 == 11) { x = dpp_i<0x128>(x); x = dpp_i<0x1B>(x); }
  else if constexpr (m4 == 12) { x = dpp_i<0x140>(x); x = dpp_i<0x1B>(x); }
  else if constexpr (m4 == 13) { x = dpp_i<0x140>(x); x = dpp_i<0x4E>(x); }
  else if constexpr (m4 == 14) { x = dpp_i<0x140>(x); x = dpp_i<0xB1>(x); }
  else if constexpr (m4 == 15) x = dpp_i<0x140>(x);
  if constexpr (ML & 16) {
    v2i r = __builtin_amdgcn_permlane16_swap(x, x, false, false);
    x = (threadIdx.x & 16) ? r.x : r.y;
  }
  if constexpr (ML & 32) {
    v2i r = __builtin_amdgcn_permlane32_swap(x, x, false, false);
    x = (threadIdx.x & 32) ? r.x : r.y;
  }
  return __int_as_float(x);
}

__device__ __forceinline__ float fetch_bp(int pa, float v) {
  return __int_as_float(__builtin_amdgcn_ds_bpermute(pa, __float_as_int(v)));
}

// cur' = c*cur + sv*t where t = (partner.im, partner.re), sv = (s, -s)
__device__ __forceinline__ v2f rxup(v2f cur, float c, v2f sv, v2f t) {
  return c * cur + sv * t;        // v_pk_mul_f32 + v_pk_fma_f32
}
__device__ __forceinline__ v2f cswap(v2f a) {
  return __builtin_shufflevector(a, a, 1, 0);
}
__device__ __forceinline__ v2f cmul(v2f a, v2f g) {
  v2f o; o.x = a.x * g.x - a.y * g.y; o.y = a.x * g.y + a.y * g.x; return o;
}

// Cross-wave exchange for one chunk pair (cA = PAIR, cB = 3-PAIR); all five
// LDS masks have reg bits [4:3] = 11 so partner chunk = chunk ^ 3. MRL = mr&7.
// Write both chunks, barrier, read partner rows, trailing barrier (buffer
// reuse by the next pair / next LDS gate).
template <int PAIR, int ML, int MRL>
__device__ __forceinline__ void xpair(v2f (&st)[32], float c, v2f sv,
                                      v2f* xbuf, int tid) {
  v2f* bufA = xbuf;
  v2f* bufB = xbuf + 8 * 128;
  constexpr int cA = PAIR, cB = 3 - PAIR;
#pragma unroll
  for (int k = 0; k < 8; ++k) bufA[k * 128 + tid] = st[8 * cA + k];
#pragma unroll
  for (int k = 0; k < 8; ++k) bufB[k * 128 + tid] = st[8 * cB + k];
  __syncthreads();
  const int ptid = tid ^ (64 | ML);
#pragma unroll
  for (int k = 0; k < 8; ++k) {
    v2f gB = bufB[k * 128 + ptid];            // partner's amp 8cB + k
    const int e = k ^ MRL;                    // serves our amp 8cA + e
    st[8 * cA + e] = rxup(st[8 * cA + e], c, sv, cswap(gB));
  }
#pragma unroll
  for (int k = 0; k < 8; ++k) {
    v2f gA = bufA[k * 128 + ptid];
    const int e = k ^ MRL;
    st[8 * cB + e] = rxup(st[8 * cB + e], c, sv, cswap(gA));
  }
  __syncthreads();
}

template <int G>
__device__ __forceinline__ void apply_gate(v2f (&st)[32], float c, v2f sv,
                                           v2f* xbuf, int tid) {
  constexpr unsigned m = MK.rx[G];
  constexpr int mw = (int)((m >> 11) & 1u);
  constexpr int ml = (int)((m >> 5) & 63u);
  constexpr int mr = (int)(m & 31u);
  if constexpr (mw) {
    static_assert((mr >> 3) == 3, "LDS gates pair chunk c with c^3");
    xpair<0, ml, (mr & 7)>(st, c, sv, xbuf, tid);
    xpair<1, ml, (mr & 7)>(st, c, sv, xbuf, tid);
  } else if constexpr (ml == 0) {
    // pure in-register pairing (12 gates)
#pragma unroll
    for (int r = 0; r < 32; ++r) {
      const int r2 = r ^ mr;
      if (r < r2) {
        v2f a = st[r], b = st[r2];
        st[r]  = rxup(a, c, sv, cswap(b));
        st[r2] = rxup(b, c, sv, cswap(a));
      }
    }
  } else if constexpr (dppcost(ml) <= 2) {
    if constexpr (mr == 0) {
      // pure cross-lane, cheap DPP/permlane
#pragma unroll
      for (int r = 0; r < 32; ++r) {
        v2f t; t.x = fetchx<ml>(st[r].y); t.y = fetchx<ml>(st[r].x);
        st[r] = rxup(st[r], c, sv, t);
      }
    } else {
      // mixed reg+lane, cheap DPP: buffer fetches per pair
#pragma unroll
      for (int r = 0; r < 32; ++r) {
        const int r2 = r ^ mr;
        if (r < r2) {
          v2f t1; t1.x = fetchx<ml>(st[r2].y); t1.y = fetchx<ml>(st[r2].x);
          v2f t2; t2.x = fetchx<ml>(st[r].y);  t2.y = fetchx<ml>(st[r].x);
          st[r]  = rxup(st[r],  c, sv, t1);
          st[r2] = rxup(st[r2], c, sv, t2);
        }
      }
    }
  } else {
    // expensive lane mask -> DS pipe (ds_bpermute), address hoisted per gate
    const int pa = ((tid & 63) ^ ml) << 2;
    if constexpr (mr == 0) {
#pragma unroll
      for (int r = 0; r < 32; ++r) {
        v2f t; t.x = fetch_bp(pa, st[r].y); t.y = fetch_bp(pa, st[r].x);
        st[r] = rxup(st[r], c, sv, t);
      }
    } else {
#pragma unroll
      for (int r = 0; r < 32; ++r) {
        const int r2 = r ^ mr;
        if (r < r2) {
          v2f t1; t1.x = fetch_bp(pa, st[r2].y); t1.y = fetch_bp(pa, st[r2].x);
          v2f t2; t2.x = fetch_bp(pa, st[r].y);  t2.y = fetch_bp(pa, st[r].x);
          st[r]  = rxup(st[r],  c, sv, t1);
          st[r2] = rxup(st[r2], c, sv, t2);
        }
      }
    }
  }
}

template <int G>
__device__ __forceinline__ void run_gates(v2f (&st)[32],
                                          const float2* __restrict__ tab,
                                          v2f* xbuf, int tid) {
  if constexpr (G < NGATES) {
    __builtin_amdgcn_sched_barrier(0);   // cap live-range hoisting (r6 lesson)
    const float2 cs = tab[G];            // uniform -> s_load, SGPR operands
    v2f sv; sv.x = cs.y; sv.y = -cs.y;
    apply_gate<G>(st, cs.x, sv, xbuf, tid);
    run_gates<G + 1>(st, tab, xbuf, tid);
  }
}

template <int W>
__device__ __forceinline__ void expvals(const float (&a2)[32], int lane, int wv,
                                        float* zb) {
  if constexpr (W < NQ) {
    constexpr unsigned zm = MK.z[W];
    constexpr int zr = (int)(zm & 31u);
    constexpr int zl = (int)((zm >> 5) & 63u);
    constexpr int zw = (int)((zm >> 11) & 1u);
    float acc = 0.f;
#pragma unroll
    for (int r = 0; r < 32; ++r) {
      if (__builtin_popcount((unsigned)(r & zr)) & 1) acc -= a2[r];
      else                                            acc += a2[r];
    }
    const int sgn = (__popc(lane & zl) ^ (wv & zw)) & 1;
    if (sgn) acc = -acc;
    {
      v2i r = __builtin_amdgcn_permlane32_swap(__float_as_int(acc),
                                               __float_as_int(acc), false, false);
      acc = __int_as_float(r.x) + __int_as_float(r.y);
    }
    {
      v2i r = __builtin_amdgcn_permlane16_swap(__float_as_int(acc),
                                               __float_as_int(acc), false, false);
      acc = __int_as_float(r.x) + __int_as_float(r.y);
    }
    acc += fetchx<8>(acc);
    acc += fetchx<4>(acc);
    acc += fetchx<2>(acc);
    acc += fetchx<1>(acc);
    if (lane == 0) zb[wv * NQ + W] = acc;
    expvals<W + 1>(a2, lane, wv, zb);
  }
}

// Per-qubit factor after RY(x_w) then layer-1 RX(wts[w]):
//   bit=0: (c*cy, -s*sy)   bit=1: (c*sy, -s*cy)
__device__ __forceinline__ void gpair(float xw, float2 cs, v2f& g0, v2f& g1) {
  float rv = xw * (0.5f * INV_2PI);
  float sy = __builtin_amdgcn_sinf(rv), cy = __builtin_amdgcn_cosf(rv);
  g0.x = cs.x * cy; g0.y = -cs.y * sy;
  g1.x = cs.x * sy; g1.y = -cs.y * cy;
}
__device__ __forceinline__ v2f gq(float xw, float2 cs, int bit) {
  v2f g0, g1; gpair(xw, cs, g0, g1);
  return bit ? g1 : g0;
}

// Prep: 48 batch-uniform gate angles -> (cos, sin) table in d_ws.
__global__ void prep_kernel(const float* __restrict__ wts,
                            float2* __restrict__ tab) {
  const int i = threadIdx.x;
  if (i < NGATES) {
    float s, c;
    __sincosf(wts[i] * 0.5f, &s, &c);
    tab[i] = make_float2(c, s);
  }
}

__global__ __attribute__((amdgpu_flat_work_group_size(128, 128),
                          amdgpu_waves_per_eu(4)))
void qsim_kernel(const float* __restrict__ x,
                 const float2* __restrict__ tab,
                 float* __restrict__ out) {
  __shared__ v2f xbuf[2 * 8 * 128];    // 16 KiB exchange double-buffer
  __shared__ float zb[2 * NQ];

  const int bidx = blockIdx.x;         // one batch element per 128-thr block
  const int tid  = threadIdx.x;
  const int lane = tid & 63;
  const int wv   = tid >> 6;

  const float4* xv = reinterpret_cast<const float4*>(x + bidx * NQ);
  float4 q0 = xv[0], q1 = xv[1], q2 = xv[2];
  const float xa[NQ] = {q0.x, q0.y, q0.z, q0.w, q1.x, q1.y, q1.z, q1.w,
                        q2.x, q2.y, q2.z, q2.w};

  // Scalar factor: p bits 6..11 (qubits 5..0) from lane/wave coords.
  const int l = lane;
  v2f F = gq(xa[5], tab[5], (l ^ (l >> 1)) & 1);          // p6 = l0^l1
  F = cmul(F, gq(xa[4], tab[4], ((l >> 1) ^ (l >> 2)) & 1));
  F = cmul(F, gq(xa[3], tab[3], ((l >> 2) ^ (l >> 3)) & 1));
  F = cmul(F, gq(xa[2], tab[2], ((l >> 3) ^ (l >> 4)) & 1));
  F = cmul(F, gq(xa[1], tab[1], ((l >> 4) ^ (l >> 5)) & 1));
  F = cmul(F, gq(xa[0], tab[0], ((l >> 5) ^ wv) & 1));    // p11 = l5^wv

  // Register doubling in y-space: p0 = r0, p_j = r_{j-1}^r_j (j=1..4).
  // Step j multiplies in qubit (11-j)'s factor; neighbor bit is compile-time.
  v2f st[32];
  st[0] = F;
#pragma unroll
  for (int j = 0; j < 4; ++j) {
    v2f g0, g1;
    gpair(xa[11 - j], tab[11 - j], g0, g1);
#pragma unroll
    for (int k = 0; k < 16; ++k) {
      if (k < (1 << j)) {
        const int b = (j == 0) ? 0 : ((k >> (j - 1)) & 1);   // r_{j-1}
        v2f base = st[k];
        st[k | (1 << j)] = cmul(base, b ? g0 : g1);          // p_j = b^1
        st[k]            = cmul(base, b ? g1 : g0);          // p_j = b
      }
    }
  }
  {
    // j=4 (qubit 7, p4 = r3^r4) fused with qubit 6 (p5 = r4 ^ l0)
    v2f g70, g71, g60, g61;
    gpair(xa[7], tab[7], g70, g71);
    gpair(xa[6], tab[6], g60, g61);
    const int l0 = l & 1;
    v2f q0v = l0 ? g61 : g60;      // G6(l0)
    v2f q1v = l0 ? g60 : g61;      // G6(l0^1)
    v2f A0 = cmul(g70, q0v), A1 = cmul(g71, q0v);
    v2f B0 = cmul(g70, q1v), B1 = cmul(g71, q1v);
#pragma unroll
    for (int k = 0; k < 16; ++k) {
      const int b3 = (k >> 3) & 1;                           // r3
      v2f base = st[k];
      st[k | 16] = cmul(base, b3 ? B0 : B1);   // G7(b3^1)*G6(l0^1)
      st[k]      = cmul(base, b3 ? A1 : A0);   // G7(b3)*G6(l0)
    }
  }

  run_gates<NQ>(st, tab, xbuf, tid);   // layers 2..4 (gates 12..47)
  __builtin_amdgcn_sched_barrier(0);

  float a2[32];
#pragma unroll
  for (int r = 0; r < 32; ++r) a2[r] = fmaf(st[r].x, st[r].x, st[r].y * st[r].y);

  expvals<0>(a2, lane, wv, zb);
  __syncthreads();
  if (tid < NQ) out[bidx * NQ + tid] = zb[tid] + zb[NQ + tid];
}

extern "C" void kernel_launch(void* const* d_in, const int* in_sizes, int n_in,
                              void* d_out, int out_size, void* d_ws, size_t ws_size,
                              hipStream_t stream) {
  const float* x   = (const float*)d_in[0];   // (4096, 12) f32
  const float* wts = (const float*)d_in[1];   // (4, 12) f32
  float* out = (float*)d_out;                 // (4096, 12) f32
  float2* tab = (float2*)d_ws;                // 48 * 8 B gate table

  prep_kernel<<<1, 64, 0, stream>>>(wts, tab);

  const int batch = in_sizes[0] / NQ;         // 4096
  dim3 grid(batch);
  dim3 block(128);
  qsim_kernel<<<grid, block, 0, stream>>>(x, tab, out);
}

// Round 11
// 103.393 us; speedup vs baseline: 1.4303x; 1.0098x over previous
//
#include <hip/hip_runtime.h>

#define NQ 12
#define NL 4
#define NGATES (NQ * NL)

// ---------------------------------------------------------------------------
// 128 threads per batch element; 32 amps/thread (64 VGPR state), 2 waves.
// GF(2) chain basis: b_k = {k,k+1} (k=0..10), b11 = {11}. Slot coords y:
//   y_j = parity(p & ((2<<j)-1)) for j<=10,  y11 = parity(p).
//   reg r = y0..y4 (32 amps), lane = y5..y10, wave = y11 (tid bit 6).
// Mask m's image = same prefix-parity transform (ytrans). Consequence:
//   {k,k+1} -> single coord bit; {k,k+2} -> 2 adjacent bits; {k..k+3} ->
//   bits k,k+2. So: 12 gates REG-PURE, 11 lane gates 1-2 DPP, 4+1 gates
//   ds_bpermute, and only FIVE wave-crossing (LDS) gates (parity-odd masks).
// Z rows contravariant: zeta_k = z_k^z_{k+1}, zeta11 = z11 (ztrans).
// Init: p0 = r0, p_j = r_{j-1}^r_j (j=1..4), p5 = r4^l0, p_{5+i} = l_{i-1}^l_i,
// p11 = l5^wv. Product state built by y-space doubling with compile-time
// neighbor bits; layer-1 RX folded in. Gate angles batch-uniform -> prep
// kernel writes (cos,sin) to d_ws, main kernel s_loads (SGPR operands).
// LDS exchange: ds b64 (v2f direct), chunk pairs (0,3),(1,2), 16KB dbuf.
// waves_per_eu(3) (~170-reg budget): round-10 used (4) -> 128 budget, and the
// allocator pinned arch VGPRs at exactly the 64-float state, pushing ALL
// temps to AGPR/scratch (64 MB writes). Demand is ~100; (3) fits it.
// ---------------------------------------------------------------------------
struct Masks { unsigned rx[NGATES]; unsigned z[NQ]; };

constexpr unsigned ytrans(unsigned m) {   // covariant: coords of m in chain basis
  unsigned e = 0;
  for (int j = 0; j <= 10; ++j)
    e |= (unsigned)(__builtin_popcount(m & ((2u << j) - 1u)) & 1) << j;
  e |= (unsigned)(__builtin_popcount(m & 0xFFFu) & 1) << 11;
  return e;
}
constexpr unsigned ztrans(unsigned z) {   // contravariant: zeta_i = z . b_i
  unsigned e = 0;
  for (int j = 0; j <= 10; ++j) e |= (((z >> j) ^ (z >> (j + 1))) & 1u) << j;
  e |= ((z >> 11) & 1u) << 11;
  return e;
}

constexpr Masks compute_masks() {
  Masks mk{};
  unsigned col[NQ] = {};
  for (int b = 0; b < NQ; ++b) col[b] = 1u << b;
  int g = 0;
  for (int l = 0; l < NL; ++l) {
    for (int w = 0; w < NQ; ++w) mk.rx[g++] = col[NQ - 1 - w];
    for (int i = 0; i < NQ; ++i) {           // ring CNOT(i, (i+1)%12)
      int cb = NQ - 1 - i;
      int tb = NQ - 1 - ((i + 1) % NQ);
      col[cb] ^= col[tb];
    }
  }
  unsigned A[NQ] = {}, Inv[NQ] = {};
  for (int i = 0; i < NQ; ++i) {
    unsigned rowv = 0;
    for (int j = 0; j < NQ; ++j) rowv |= ((col[j] >> i) & 1u) << j;
    A[i] = rowv;
    Inv[i] = 1u << i;
  }
  for (int c = 0; c < NQ; ++c) {
    int piv = c;
    while (((A[piv] >> c) & 1u) == 0u) ++piv;
    unsigned ta = A[piv]; A[piv] = A[c]; A[c] = ta;
    unsigned ti = Inv[piv]; Inv[piv] = Inv[c]; Inv[c] = ti;
    for (int r = 0; r < NQ; ++r)
      if (r != c && ((A[r] >> c) & 1u)) { A[r] ^= A[c]; Inv[r] ^= Inv[c]; }
  }
  for (int w = 0; w < NQ; ++w) mk.z[w] = ztrans(Inv[NQ - 1 - w]);
  for (int i = 0; i < NGATES; ++i) mk.rx[i] = ytrans(mk.rx[i]);
  return mk;
}

constexpr Masks MK = compute_masks();

typedef float v2f __attribute__((ext_vector_type(2)));
typedef int   v2i __attribute__((ext_vector_type(2)));

#define INV_2PI 0.15915494309189535f

template <int CTRL>
__device__ __forceinline__ int dpp_i(int x) {
  return __builtin_amdgcn_update_dpp(x, x, CTRL, 0xf, 0xf, false);
}

// VALU cost of a cross-lane xor-mask fetch (DPP/permlane path).
constexpr int dppcost(int ml) {
  int m4 = ml & 15;
  int c = (m4 == 0) ? 0
        : ((m4 == 1 || m4 == 2 || m4 == 3 || m4 == 7 || m4 == 8 || m4 == 15) ? 1 : 2);
  if (ml & 16) c += 2;
  if (ml & 32) c += 2;
  return c;
}

// v[lane ^ ML] on the VALU pipe. quad_perm xor1=0xB1 xor2=0x4E xor3=0x1B;
// row_half_mirror(xor7)=0x141; row_ror:8(xor8)=0x128; row_mirror(xor15)=0x140.
template <int ML>
__device__ __forceinline__ float fetchx(float v) {
  static_assert(ML >= 1 && ML < 64, "lane mask");
  int x = __float_as_int(v);
  constexpr int m4 = ML & 15;
  if constexpr (m4 == 1)       x = dpp_i<0xB1>(x);
  else if constexpr (m4 == 2)  x = dpp_i<0x4E>(x);
  else if constexpr (m4 == 3)  x = dpp_i<0x1B>(x);
  else if constexpr (m4 == 4)  { x = dpp_i<0x141>(x); x = dpp_i<0x1B>(x); }
  else if constexpr (m4 == 5)  { x = dpp_i<0x141>(x); x = dpp_i<0x4E>(x); }
  else if constexpr (m4 == 6)  { x = dpp_i<0x141>(x); x = dpp_i<0xB1>(x); }
  else if constexpr (m4 == 7)  x = dpp_i<0x141>(x);
  else if constexpr (m4 == 8)  x = dpp_i<0x128>(x);
  else if constexpr (m4 == 9)  { x = dpp_i<0x128>(x); x = dpp_i<0xB1>(x); }
  else if constexpr (m4 == 10) { x = dpp_i<0x128>(x); x = dpp_i<0x4E>(x); }
  else if constexpr (m4 == 11) { x = dpp_i<0x128>(x); x = dpp_i<0x1B>(x); }
  else if constexpr (m4 == 12) { x = dpp_i<0x140>(x); x = dpp_i<0x1B>(x); }
  else if constexpr (m4 == 13) { x = dpp_i<0x140>(x); x = dpp_i<0x4E>(x); }
  else if constexpr (m4 == 14) { x = dpp_i<0x140>(x); x = dpp_i<0xB1>(x); }
  else if constexpr (m4 == 15) x = dpp_i<0x140>(x);
  if constexpr (ML & 16) {
    v2i r = __builtin_amdgcn_permlane16_swap(x, x, false, false);
    x = (threadIdx.x & 16) ? r.x : r.y;
  }
  if constexpr (ML & 32) {
    v2i r = __builtin_amdgcn_permlane32_swap(x, x, false, false);
    x = (threadIdx.x & 32) ? r.x : r.y;
  }
  return __int_as_float(x);
}

__device__ __forceinline__ float fetch_bp(int pa, float v) {
  return __int_as_float(__builtin_amdgcn_ds_bpermute(pa, __float_as_int(v)));
}

// cur' = c*cur + sv*t where t = (partner.im, partner.re), sv = (s, -s)
__device__ __forceinline__ v2f rxup(v2f cur, float c, v2f sv, v2f t) {
  return c * cur + sv * t;        // v_pk_mul_f32 + v_pk_fma_f32
}
__device__ __forceinline__ v2f cswap(v2f a) {
  return __builtin_shufflevector(a, a, 1, 0);
}
__device__ __forceinline__ v2f cmul(v2f a, v2f g) {
  v2f o; o.x = a.x * g.x - a.y * g.y; o.y = a.x * g.y + a.y * g.x; return o;
}

// Cross-wave exchange for one chunk pair (cA = PAIR, cB = 3-PAIR); all five
// LDS masks have reg bits [4:3] = 11 so partner chunk = chunk ^ 3. MRL = mr&7.
// Write both chunks, barrier, read partner rows, trailing barrier (buffer
// reuse by the next pair / next LDS gate).
template <int PAIR, int ML, int MRL>
__device__ __forceinline__ void xpair(v2f (&st)[32], float c, v2f sv,
                                      v2f* xbuf, int tid) {
  v2f* bufA = xbuf;
  v2f* bufB = xbuf + 8 * 128;
  constexpr int cA = PAIR, cB = 3 - PAIR;
#pragma unroll
  for (int k = 0; k < 8; ++k) bufA[k * 128 + tid] = st[8 * cA + k];
#pragma unroll
  for (int k = 0; k < 8; ++k) bufB[k * 128 + tid] = st[8 * cB + k];
  __syncthreads();
  const int ptid = tid ^ (64 | ML);
#pragma unroll
  for (int k = 0; k < 8; ++k) {
    v2f gB = bufB[k * 128 + ptid];            // partner's amp 8cB + k
    const int e = k ^ MRL;                    // serves our amp 8cA + e
    st[8 * cA + e] = rxup(st[8 * cA + e], c, sv, cswap(gB));
  }
#pragma unroll
  for (int k = 0; k < 8; ++k) {
    v2f gA = bufA[k * 128 + ptid];
    const int e = k ^ MRL;
    st[8 * cB + e] = rxup(st[8 * cB + e], c, sv, cswap(gA));
  }
  __syncthreads();
}

template <int G>
__device__ __forceinline__ void apply_gate(v2f (&st)[32], float c, v2f sv,
                                           v2f* xbuf, int tid) {
  constexpr unsigned m = MK.rx[G];
  constexpr int mw = (int)((m >> 11) & 1u);
  constexpr int ml = (int)((m >> 5) & 63u);
  constexpr int mr = (int)(m & 31u);
  if constexpr (mw) {
    static_assert((mr >> 3) == 3, "LDS gates pair chunk c with c^3");
    xpair<0, ml, (mr & 7)>(st, c, sv, xbuf, tid);
    xpair<1, ml, (mr & 7)>(st, c, sv, xbuf, tid);
  } else if constexpr (ml == 0) {
    // pure in-register pairing (12 gates)
#pragma unroll
    for (int r = 0; r < 32; ++r) {
      const int r2 = r ^ mr;
      if (r < r2) {
        v2f a = st[r], b = st[r2];
        st[r]  = rxup(a, c, sv, cswap(b));
        st[r2] = rxup(b, c, sv, cswap(a));
      }
    }
  } else if constexpr (dppcost(ml) <= 2) {
    if constexpr (mr == 0) {
      // pure cross-lane, cheap DPP/permlane
#pragma unroll
      for (int r = 0; r < 32; ++r) {
        v2f t; t.x = fetchx<ml>(st[r].y); t.y = fetchx<ml>(st[r].x);
        st[r] = rxup(st[r], c, sv, t);
      }
    } else {
      // mixed reg+lane, cheap DPP: buffer fetches per pair
#pragma unroll
      for (int r = 0; r < 32; ++r) {
        const int r2 = r ^ mr;
        if (r < r2) {
          v2f t1; t1.x = fetchx<ml>(st[r2].y); t1.y = fetchx<ml>(st[r2].x);
          v2f t2; t2.x = fetchx<ml>(st[r].y);  t2.y = fetchx<ml>(st[r].x);
          st[r]  = rxup(st[r],  c, sv, t1);
          st[r2] = rxup(st[r2], c, sv, t2);
        }
      }
    }
  } else {
    // expensive lane mask -> DS pipe (ds_bpermute), address hoisted per gate
    const int pa = ((tid & 63) ^ ml) << 2;
    if constexpr (mr == 0) {
#pragma unroll
      for (int r = 0; r < 32; ++r) {
        v2f t; t.x = fetch_bp(pa, st[r].y); t.y = fetch_bp(pa, st[r].x);
        st[r] = rxup(st[r], c, sv, t);
      }
    } else {
#pragma unroll
      for (int r = 0; r < 32; ++r) {
        const int r2 = r ^ mr;
        if (r < r2) {
          v2f t1; t1.x = fetch_bp(pa, st[r2].y); t1.y = fetch_bp(pa, st[r2].x);
          v2f t2; t2.x = fetch_bp(pa, st[r].y);  t2.y = fetch_bp(pa, st[r].x);
          st[r]  = rxup(st[r],  c, sv, t1);
          st[r2] = rxup(st[r2], c, sv, t2);
        }
      }
    }
  }
}

template <int G>
__device__ __forceinline__ void run_gates(v2f (&st)[32],
                                          const float2* __restrict__ tab,
                                          v2f* xbuf, int tid) {
  if constexpr (G < NGATES) {
    __builtin_amdgcn_sched_barrier(0);   // cap live-range hoisting (r6 lesson)
    const float2 cs = tab[G];            // uniform -> s_load, SGPR operands
    v2f sv; sv.x = cs.y; sv.y = -cs.y;
    apply_gate<G>(st, cs.x, sv, xbuf, tid);
    run_gates<G + 1>(st, tab, xbuf, tid);
  }
}

template <int W>
__device__ __forceinline__ void expvals(const float (&a2)[32], int lane, int wv,
                                        float* zb) {
  if constexpr (W < NQ) {
    constexpr unsigned zm = MK.z[W];
    constexpr int zr = (int)(zm & 31u);
    constexpr int zl = (int)((zm >> 5) & 63u);
    constexpr int zw = (int)((zm >> 11) & 1u);
    float acc = 0.f;
#pragma unroll
    for (int r = 0; r < 32; ++r) {
      if (__builtin_popcount((unsigned)(r & zr)) & 1) acc -= a2[r];
      else                                            acc += a2[r];
    }
    const int sgn = (__popc(lane & zl) ^ (wv & zw)) & 1;
    if (sgn) acc = -acc;
    {
      v2i r = __builtin_amdgcn_permlane32_swap(__float_as_int(acc),
                                               __float_as_int(acc), false, false);
      acc = __int_as_float(r.x) + __int_as_float(r.y);
    }
    {
      v2i r = __builtin_amdgcn_permlane16_swap(__float_as_int(acc),
                                               __float_as_int(acc), false, false);
      acc = __int_as_float(r.x) + __int_as_float(r.y);
    }
    acc += fetchx<8>(acc);
    acc += fetchx<4>(acc);
    acc += fetchx<2>(acc);
    acc += fetchx<1>(acc);
    if (lane == 0) zb[wv * NQ + W] = acc;
    expvals<W + 1>(a2, lane, wv, zb);
  }
}

// Per-qubit factor after RY(x_w) then layer-1 RX(wts[w]):
//   bit=0: (c*cy, -s*sy)   bit=1: (c*sy, -s*cy)
__device__ __forceinline__ void gpair(float xw, float2 cs, v2f& g0, v2f& g1) {
  float rv = xw * (0.5f * INV_2PI);
  float sy = __builtin_amdgcn_sinf(rv), cy = __builtin_amdgcn_cosf(rv);
  g0.x = cs.x * cy; g0.y = -cs.y * sy;
  g1.x = cs.x * sy; g1.y = -cs.y * cy;
}
__device__ __forceinline__ v2f gq(float xw, float2 cs, int bit) {
  v2f g0, g1; gpair(xw, cs, g0, g1);
  return bit ? g1 : g0;
}

// Prep: 48 batch-uniform gate angles -> (cos, sin) table in d_ws.
__global__ void prep_kernel(const float* __restrict__ wts,
                            float2* __restrict__ tab) {
  const int i = threadIdx.x;
  if (i < NGATES) {
    float s, c;
    __sincosf(wts[i] * 0.5f, &s, &c);
    tab[i] = make_float2(c, s);
  }
}

__global__ __attribute__((amdgpu_flat_work_group_size(128, 128),
                          amdgpu_waves_per_eu(3)))
void qsim_kernel(const float* __restrict__ x,
                 const float2* __restrict__ tab,
                 float* __restrict__ out) {
  __shared__ v2f xbuf[2 * 8 * 128];    // 16 KiB exchange double-buffer
  __shared__ float zb[2 * NQ];

  const int bidx = blockIdx.x;         // one batch element per 128-thr block
  const int tid  = threadIdx.x;
  const int lane = tid & 63;
  const int wv   = tid >> 6;

  const float4* xv = reinterpret_cast<const float4*>(x + bidx * NQ);
  float4 q0 = xv[0], q1 = xv[1], q2 = xv[2];
  const float xa[NQ] = {q0.x, q0.y, q0.z, q0.w, q1.x, q1.y, q1.z, q1.w,
                        q2.x, q2.y, q2.z, q2.w};

  // Scalar factor: p bits 6..11 (qubits 5..0) from lane/wave coords.
  const int l = lane;
  v2f F = gq(xa[5], tab[5], (l ^ (l >> 1)) & 1);          // p6 = l0^l1
  F = cmul(F, gq(xa[4], tab[4], ((l >> 1) ^ (l >> 2)) & 1));
  F = cmul(F, gq(xa[3], tab[3], ((l >> 2) ^ (l >> 3)) & 1));
  F = cmul(F, gq(xa[2], tab[2], ((l >> 3) ^ (l >> 4)) & 1));
  F = cmul(F, gq(xa[1], tab[1], ((l >> 4) ^ (l >> 5)) & 1));
  F = cmul(F, gq(xa[0], tab[0], ((l >> 5) ^ wv) & 1));    // p11 = l5^wv

  // Register doubling in y-space: p0 = r0, p_j = r_{j-1}^r_j (j=1..4).
  // Step j multiplies in qubit (11-j)'s factor; neighbor bit is compile-time.
  v2f st[32];
  st[0] = F;
#pragma unroll
  for (int j = 0; j < 4; ++j) {
    v2f g0, g1;
    gpair(xa[11 - j], tab[11 - j], g0, g1);
#pragma unroll
    for (int k = 0; k < 16; ++k) {
      if (k < (1 << j)) {
        const int b = (j == 0) ? 0 : ((k >> (j - 1)) & 1);   // r_{j-1}
        v2f base = st[k];
        st[k | (1 << j)] = cmul(base, b ? g0 : g1);          // p_j = b^1
        st[k]            = cmul(base, b ? g1 : g0);          // p_j = b
      }
    }
  }
  {
    // j=4 (qubit 7, p4 = r3^r4) fused with qubit 6 (p5 = r4 ^ l0)
    v2f g70, g71, g60, g61;
    gpair(xa[7], tab[7], g70, g71);
    gpair(xa[6], tab[6], g60, g61);
    const int l0 = l & 1;
    v2f q0v = l0 ? g61 : g60;      // G6(l0)
    v2f q1v = l0 ? g60 : g61;      // G6(l0^1)
    v2f A0 = cmul(g70, q0v), A1 = cmul(g71, q0v);
    v2f B0 = cmul(g70, q1v), B1 = cmul(g71, q1v);
#pragma unroll
    for (int k = 0; k < 16; ++k) {
      const int b3 = (k >> 3) & 1;                           // r3
      v2f base = st[k];
      st[k | 16] = cmul(base, b3 ? B0 : B1);   // G7(b3^1)*G6(l0^1)
      st[k]      = cmul(base, b3 ? A1 : A0);   // G7(b3)*G6(l0)
    }
  }

  run_gates<NQ>(st, tab, xbuf, tid);   // layers 2..4 (gates 12..47)
  __builtin_amdgcn_sched_barrier(0);

  float a2[32];
#pragma unroll
  for (int r = 0; r < 32; ++r) a2[r] = fmaf(st[r].x, st[r].x, st[r].y * st[r].y);

  expvals<0>(a2, lane, wv, zb);
  __syncthreads();
  if (tid < NQ) out[bidx * NQ + tid] = zb[tid] + zb[NQ + tid];
}

extern "C" void kernel_launch(void* const* d_in, const int* in_sizes, int n_in,
                              void* d_out, int out_size, void* d_ws, size_t ws_size,
                              hipStream_t stream) {
  const float* x   = (const float*)d_in[0];   // (4096, 12) f32
  const float* wts = (const float*)d_in[1];   // (4, 12) f32
  float* out = (float*)d_out;                 // (4096, 12) f32
  float2* tab = (float2*)d_ws;                // 48 * 8 B gate table

  prep_kernel<<<1, 64, 0, stream>>>(wts, tab);

  const int batch = in_sizes[0] / NQ;         // 4096
  dim3 grid(batch);
  dim3 block(128);
  qsim_kernel<<<grid, block, 0, stream>>>(x, tab, out);
}